// Round 10
// baseline (384.413 us; speedup 1.0000x reference)
//
#include <hip/hip_runtime.h>
#include <hip/hip_bf16.h>

#define S_LEN 2048
#define DMODEL 768
#define NHEAD 12
#define DKH 64
#define DFF_K 3072
#define MROWS 4096   // B*S
#define KSPLIT 2
#define KHALF (S_LEN / KSPLIT)

typedef __attribute__((ext_vector_type(8))) short bf16x8;
typedef __attribute__((ext_vector_type(8))) unsigned short us8;
typedef __attribute__((ext_vector_type(4))) float f32x4;

__device__ __forceinline__ float bfu2f(unsigned short u) {
  return __uint_as_float(((unsigned int)u) << 16);
}
__device__ __forceinline__ unsigned short f2bfu(float f) {
  __hip_bfloat16 h = __float2bfloat16(f);
  return *reinterpret_cast<unsigned short*>(&h);
}

// async global->LDS 16B: LDS dest is wave-uniform base + lane*16 (HW rule)
__device__ __forceinline__ void async16(const unsigned short* g, unsigned short* l) {
  __builtin_amdgcn_global_load_lds(
      (const __attribute__((address_space(1))) unsigned int*)g,
      (__attribute__((address_space(3))) unsigned int*)l, 16, 0, 0);
}

// ---------------------------------------------------------------------------
// fp32 -> bf16 elementwise convert
// ---------------------------------------------------------------------------
__global__ __launch_bounds__(256) void convert_kernel(
    const float* __restrict__ in, unsigned short* __restrict__ out, int n4)
{
  const int i = blockIdx.x * 256 + threadIdx.x;
  if (i < n4) {
    float4 v = *(const float4*)(in + (size_t)i * 4);
    ushort4 o;
    o.x = f2bfu(v.x); o.y = f2bfu(v.y); o.z = f2bfu(v.z); o.w = f2bfu(v.w);
    *(ushort4*)(out + (size_t)i * 4) = o;
  }
}

// ---------------------------------------------------------------------------
// fp32 [R][C] -> bf16 [C][R] transpose-convert (generic, head or flat).
// ---------------------------------------------------------------------------
__device__ __forceinline__ void transpose_conv_body(
    const float* in, unsigned short* out, int R, int Ctot, int head,
    int bx, int by, int tid)
{
  __shared__ float t[64][68];
  const int r0 = bx * 64;
  const int c0 = by * 64;
  const float* ib;
  int ld;
  if (head) { ib = in + (size_t)by * R * 64; ld = 64; }
  else      { ib = in + c0;                  ld = Ctot; }
  const int lr = tid >> 4;
  const int lc = (tid & 15) << 2;

#pragma unroll
  for (int rr = 0; rr < 4; ++rr) {
    const int row = rr * 16 + lr;
    float4 v = *(const float4*)(ib + (size_t)(r0 + row) * ld + lc);
    t[row][lc + 0] = v.x; t[row][lc + 1] = v.y;
    t[row][lc + 2] = v.z; t[row][lc + 3] = v.w;
  }
  __syncthreads();
#pragma unroll
  for (int rr = 0; rr < 4; ++rr) {
    const int oc = rr * 16 + lr;
    ushort4 o;
    o.x = f2bfu(t[lc + 0][oc]); o.y = f2bfu(t[lc + 1][oc]);
    o.z = f2bfu(t[lc + 2][oc]); o.w = f2bfu(t[lc + 3][oc]);
    *(ushort4*)(out + (size_t)(c0 + oc) * R + r0 + lc) = o;
  }
}

__global__ __launch_bounds__(256) void transpose_conv_kernel(
    const float* __restrict__ in, unsigned short* __restrict__ out,
    int R, int Ctot, int head)
{
  transpose_conv_body(in, out, R, Ctot, head, blockIdx.x, blockIdx.y, threadIdx.x);
}

// fused Wq/Wk/Wv/Wo transpose: z selects tensor; z<3 head-mode
__global__ __launch_bounds__(256) void transpose_conv4_kernel(
    const float* __restrict__ i0, const float* __restrict__ i1,
    const float* __restrict__ i2, const float* __restrict__ i3,
    unsigned short* __restrict__ o0, unsigned short* __restrict__ o1,
    unsigned short* __restrict__ o2, unsigned short* __restrict__ o3)
{
  const int z = blockIdx.z;
  const float* in = (z == 0) ? i0 : (z == 1) ? i1 : (z == 2) ? i2 : i3;
  unsigned short* out = (z == 0) ? o0 : (z == 1) ? o1 : (z == 2) ? o2 : o3;
  transpose_conv_body(in, out, DMODEL, DMODEL, (z < 3) ? 1 : 0,
                      blockIdx.x, blockIdx.y, threadIdx.x);
}

// ---------------------------------------------------------------------------
// Stage one BK=64 tile pair (A: 128 rows, B: BN rows, 64 cols bf16) into
// linear LDS via global_load_lds width-16. Global source is inverse-XOR-
// swizzled (slot ^= row&7) so that swizzled ds_reads see linear data.
// Per-thread instruction count: 4 + BN/32 (6 for BN=64, 8 for BN=128).
// ---------------------------------------------------------------------------
template<int BN>
__device__ __forceinline__ void stage_tile(
    const unsigned short* __restrict__ Ab,   // A + row0*K (+0), element ptr
    const unsigned short* __restrict__ Bb,   // BT + col0*K
    unsigned short* As, unsigned short* Bs,  // LDS linear [rows][64]
    int wid, int lane, int K, int kofs)      // kofs in elements
{
  const int r = lane >> 3;
  const int s = lane & 7;
#pragma unroll
  for (int p = 0; p < 4; ++p) {
    const int row = wid * 32 + p * 8 + r;
    async16(Ab + (size_t)row * K + kofs + ((s ^ (row & 7)) << 3),
            As + (size_t)(wid * 32 + p * 8) * 64);
  }
#pragma unroll
  for (int p = 0; p < BN / 32; ++p) {
    const int row = wid * (BN / 4) + p * 8 + r;
    async16(Bb + (size_t)row * K + kofs + ((s ^ (row & 7)) << 3),
            Bs + (size_t)(wid * (BN / 4) + p * 8) * 64);
  }
}

// ---------------------------------------------------------------------------
// MFMA bf16 GEMM, BK=64, double-buffered LDS filled by global_load_lds,
// XOR-swizzled reads, COUNTED-vmcnt pipeline: next tile's stage loads stay
// in flight across both barriers (proven round-5 structure).
// C = act(A[M x K] @ BT[N x K]^T + bias). BM=128, BN template (64 or 128).
// Grid: x = M row-block, y = N col-block, z = K-split
// (partial z -> C + z*out_stride; bias from z==0 only).
// ---------------------------------------------------------------------------
template<int BN>
__global__ __launch_bounds__(256) void mfma_gemm_kernel(
    const unsigned short* __restrict__ A,
    const unsigned short* __restrict__ BT,
    const float* __restrict__ bias,
    unsigned short* __restrict__ C,
    int K, int N, int relu, int klen, size_t out_stride)
{
  constexpr int WN = (BN == 128) ? 64 : 32;
  constexpr int NJ = WN / 16;
  __shared__ unsigned short As[2][128][64];
  __shared__ unsigned short Bs[2][BN][64];

  const int tid  = threadIdx.x;
  const int wid  = tid >> 6;
  const int lane = tid & 63;
  const int ml   = lane & 15;
  const int quad = lane >> 4;
  const int wm   = (wid & 1) * 64;
  const int wn   = (wid >> 1) * WN;
  const int row0 = blockIdx.x * 128;
  const int col0 = blockIdx.y * BN;
  const int zed  = blockIdx.z;
  const int kb0  = zed * klen;
  const int nsteps = klen >> 6;
  const int fsw = (ml & 7) << 4;   // fragment-read swizzle (row&7 == ml&7)

  const unsigned short* Ab = A  + (size_t)row0 * K + kb0;
  const unsigned short* Bb = BT + (size_t)col0 * K + kb0;

  f32x4 acc[4][NJ];
#pragma unroll
  for (int i = 0; i < 4; ++i)
#pragma unroll
    for (int j = 0; j < NJ; ++j)
#pragma unroll
      for (int r = 0; r < 4; ++r) acc[i][j][r] = 0.f;

  stage_tile<BN>(Ab, Bb, &As[0][0][0], &Bs[0][0][0], wid, lane, K, 0);

  for (int st = 0; st < nsteps; ++st) {
    const int cur = st & 1;
    if (st + 1 < nsteps) {
      stage_tile<BN>(Ab, Bb, &As[cur ^ 1][0][0], &Bs[cur ^ 1][0][0],
                     wid, lane, K, (st + 1) << 6);
      if constexpr (BN == 128) { asm volatile("s_waitcnt vmcnt(8)" ::: "memory"); }
      else                     { asm volatile("s_waitcnt vmcnt(6)" ::: "memory"); }
    } else {
      asm volatile("s_waitcnt vmcnt(0)" ::: "memory");
    }
    __builtin_amdgcn_s_barrier();   // all waves: stage(t) landed in LDS

    const char* Ac = (const char*)&As[cur][0][0];
    const char* Bc = (const char*)&Bs[cur][0][0];
#pragma unroll
    for (int h = 0; h < 2; ++h) {
      bf16x8 af[4], bfr[NJ];
#pragma unroll
      for (int i = 0; i < 4; ++i) {
        const int ar = wm + i * 16 + ml;
        af[i] = *(const bf16x8*)(Ac + ar * 128 + (((h << 6) + (quad << 4)) ^ fsw));
      }
#pragma unroll
      for (int j = 0; j < NJ; ++j) {
        const int br = wn + j * 16 + ml;
        bfr[j] = *(const bf16x8*)(Bc + br * 128 + (((h << 6) + (quad << 4)) ^ fsw));
      }
#pragma unroll
      for (int i = 0; i < 4; ++i)
#pragma unroll
        for (int j = 0; j < NJ; ++j)
          acc[i][j] = __builtin_amdgcn_mfma_f32_16x16x32_bf16(
              af[i], bfr[j], acc[i][j], 0, 0, 0);
    }
    __builtin_amdgcn_s_barrier();   // readers of buf[cur] done
  }

  unsigned short* Cz = C + (size_t)zed * out_stride;
#pragma unroll
  for (int j = 0; j < NJ; ++j) {
    const int col = col0 + wn + j * 16 + ml;
    const float bb = (zed == 0) ? bias[col] : 0.f;
#pragma unroll
    for (int i = 0; i < 4; ++i) {
      const int r0g = row0 + wm + i * 16 + (quad << 2);
#pragma unroll
      for (int r = 0; r < 4; ++r) {
        float v = acc[i][j][r] + bb;
        if (relu) v = fmaxf(v, 0.f);
        Cz[(size_t)(r0g + r) * N + col] = f2bfu(v);
      }
    }
  }
}

// fused QKV projection (per-z, 1152 blocks): z=0 -> Q, z=1 -> K, z=2 -> V
// (VT store). BN=64, BK=64 gload_lds staging + counted vmcnt.
__global__ __launch_bounds__(256) void qkv_gemm_kernel(
    const unsigned short* __restrict__ A,
    const unsigned short* __restrict__ W0, const unsigned short* __restrict__ W1,
    const unsigned short* __restrict__ W2,
    const float* __restrict__ bq, const float* __restrict__ bk,
    const float* __restrict__ bv,
    unsigned short* __restrict__ C0, unsigned short* __restrict__ C1,
    unsigned short* __restrict__ C2)
{
  __shared__ unsigned short As[2][128][64];
  __shared__ unsigned short Bs[2][64][64];
  const int z = blockIdx.z;
  const unsigned short* BT = (z == 0) ? W0 : (z == 1) ? W1 : W2;
  const float* bias = (z == 0) ? bq : (z == 1) ? bk : bv;
  unsigned short* C = (z == 0) ? C0 : (z == 1) ? C1 : C2;
  const int K = DMODEL, N = DMODEL;

  const int tid  = threadIdx.x;
  const int wid  = tid >> 6;
  const int lane = tid & 63;
  const int ml   = lane & 15;
  const int quad = lane >> 4;
  const int wm   = (wid & 1) * 64;
  const int wn   = (wid >> 1) * 32;
  const int row0 = blockIdx.x * 128;
  const int col0 = blockIdx.y * 64;
  const int fsw = (ml & 7) << 4;

  const unsigned short* Ab = A  + (size_t)row0 * K;
  const unsigned short* Bb = BT + (size_t)col0 * K;

  f32x4 acc[4][2];
#pragma unroll
  for (int i = 0; i < 4; ++i)
#pragma unroll
    for (int j = 0; j < 2; ++j)
#pragma unroll
      for (int r = 0; r < 4; ++r) acc[i][j][r] = 0.f;

  stage_tile<64>(Ab, Bb, &As[0][0][0], &Bs[0][0][0], wid, lane, K, 0);

  const int nsteps = K >> 6;   // 12
  for (int st = 0; st < nsteps; ++st) {
    const int cur = st & 1;
    if (st + 1 < nsteps) {
      stage_tile<64>(Ab, Bb, &As[cur ^ 1][0][0], &Bs[cur ^ 1][0][0],
                     wid, lane, K, (st + 1) << 6);
      asm volatile("s_waitcnt vmcnt(6)" ::: "memory");
    } else {
      asm volatile("s_waitcnt vmcnt(0)" ::: "memory");
    }
    __builtin_amdgcn_s_barrier();

    const char* Ac = (const char*)&As[cur][0][0];
    const char* Bc = (const char*)&Bs[cur][0][0];
#pragma unroll
    for (int h = 0; h < 2; ++h) {
      bf16x8 af[4], bfr[2];
#pragma unroll
      for (int i = 0; i < 4; ++i) {
        const int ar = wm + i * 16 + ml;
        af[i] = *(const bf16x8*)(Ac + ar * 128 + (((h << 6) + (quad << 4)) ^ fsw));
      }
#pragma unroll
      for (int j = 0; j < 2; ++j) {
        const int br = wn + j * 16 + ml;
        bfr[j] = *(const bf16x8*)(Bc + br * 128 + (((h << 6) + (quad << 4)) ^ fsw));
      }
#pragma unroll
      for (int i = 0; i < 4; ++i)
#pragma unroll
        for (int j = 0; j < 2; ++j)
          acc[i][j] = __builtin_amdgcn_mfma_f32_16x16x32_bf16(
              af[i], bfr[j], acc[i][j], 0, 0, 0);
    }
    __builtin_amdgcn_s_barrier();
  }

#pragma unroll
  for (int j = 0; j < 2; ++j) {
    const int col = col0 + wn + j * 16 + ml;
    const float bb = bias[col];
#pragma unroll
    for (int i = 0; i < 4; ++i) {
      const int r0g = row0 + wm + i * 16 + (quad << 2);
      if (z == 2) {
        const int bb_ = r0g >> 11, s = r0g & 2047;
        const int hh = col >> 6, dd = col & 63;
        ushort4 o;
        o.x = f2bfu(acc[i][j][0] + bb); o.y = f2bfu(acc[i][j][1] + bb);
        o.z = f2bfu(acc[i][j][2] + bb); o.w = f2bfu(acc[i][j][3] + bb);
        *(ushort4*)(C + ((size_t)((bb_ * NHEAD + hh) * DKH + dd)) * S_LEN + s) = o;
      } else {
#pragma unroll
        for (int r = 0; r < 4; ++r)
          C[(size_t)(r0g + r) * N + col] = f2bfu(acc[i][j][r] + bb);
      }
    }
  }
}

// ---------------------------------------------------------------------------
// MFMA flash attention v6: v4 structure (16x16 MFMA, K/V dbuf, 1 barrier/
// tile -- proven 53.3us) with QP HALVED to 8KB by sequencing PV as A-then-B
// through one per-wave buffer (V fragments hoisted to regs so they are read
// once). LDS 40KB -> exactly 4 blocks/CU (was 3). v5's 32x32 in-reg-P
// variant REGRESSED (55.6us: dependent 8-cyc MFMA chains + exchange VALU).
// Grid: x = head, y = batch, z = qtile128*KSPLIT + split.
// ---------------------------------------------------------------------------
#define SCL2E 0.1803368822f   // 0.125 * log2(e)
__global__ __launch_bounds__(256, 4) void flash_attn_mfma(
    const unsigned short* __restrict__ Q,
    const unsigned short* __restrict__ K,
    const unsigned short* __restrict__ VT,
    float* __restrict__ Opart,      // [KSPLIT][B][H][S][DKH] f32, unnormalized
    float* __restrict__ Lpart)      // [KSPLIT][B][H][S] f32
{
  __shared__ unsigned short Ks[2][64][64];     // 16 KB
  __shared__ unsigned short Vs[2][64][64];     // 16 KB  (VT tile: [d][t])
  __shared__ unsigned short QP[4][16][64];     //  8 KB  per-wave P^T (A then B)

  const int tid  = threadIdx.x;
  const int wid  = tid >> 6;
  const int lane = tid & 63;
  const int ml   = lane & 15;
  const int quad = lane >> 4;
  const int h    = blockIdx.x, b = blockIdx.y;
  const int q0   = (blockIdx.z >> 1) * 128;
  const int ks   = blockIdx.z & 1;
  const int kt0  = ks * KHALF;

  const size_t qkbase = ((size_t)b * S_LEN) * DMODEL + (size_t)h * DKH;
  const size_t vtbase = ((size_t)(b * NHEAD + h)) * DKH * S_LEN;

  const int sr  = tid >> 2;          // 0..63 staging row
  const int scb = (tid & 3) << 5;    // staging byte col: 0,32,64,96
  const int ssw = (sr & 7) << 4;     // staging swizzle
  const int fsw = (ml & 7) << 4;     // fragment-row swizzle (row&7 == ml&7)

  // ---- Q fragments direct from global (once per block) ----
  const int qrA = q0 + wid * 32 + ml;
  const int qrB = qrA + 16;
  const unsigned short* qpg = Q + qkbase;
  bf16x8 qfA0 = *(const bf16x8*)(qpg + (size_t)qrA * DMODEL + (quad << 3));
  bf16x8 qfA1 = *(const bf16x8*)(qpg + (size_t)qrA * DMODEL + 32 + (quad << 3));
  bf16x8 qfB0 = *(const bf16x8*)(qpg + (size_t)qrB * DMODEL + (quad << 3));
  bf16x8 qfB1 = *(const bf16x8*)(qpg + (size_t)qrB * DMODEL + 32 + (quad << 3));

  const unsigned short* pK = K + qkbase + (size_t)(kt0 + sr) * DMODEL + (scb >> 1);
  const unsigned short* pV = VT + vtbase + (size_t)sr * S_LEN + kt0 + (scb >> 1);

  float lsumA = 0.f, lsumB = 0.f;
  f32x4 oaccA[4], oaccB[4];
#pragma unroll
  for (int dt = 0; dt < 4; ++dt)
#pragma unroll
    for (int r = 0; r < 4; ++r) { oaccA[dt][r] = 0.f; oaccB[dt][r] = 0.f; }

  char* qp = (char*)&QP[wid][ml][0];

  // ---- prologue: tile0 -> regs -> buf0; tile1 -> regs; barrier ----
  us8 rk0 = *(const us8*)(pK);
  us8 rk1 = *(const us8*)(pK + 8);
  us8 rv0 = *(const us8*)(pV);
  us8 rv1 = *(const us8*)(pV + 8);
  {
    char* kw = (char*)&Ks[0][sr][0];
    char* vw = (char*)&Vs[0][sr][0];
    *(us8*)(kw + ((scb +  0) ^ ssw)) = rk0;
    *(us8*)(kw + ((scb + 16) ^ ssw)) = rk1;
    *(us8*)(vw + ((scb +  0) ^ ssw)) = rv0;
    *(us8*)(vw + ((scb + 16) ^ ssw)) = rv1;
  }
  rk0 = *(const us8*)(pK + (size_t)64 * DMODEL);
  rk1 = *(const us8*)(pK + (size_t)64 * DMODEL + 8);
  rv0 = *(const us8*)(pV + 64);
  rv1 = *(const us8*)(pV + 64 + 8);
  __syncthreads();

  const int NT = KHALF / 64;   // 16
  for (int t = 0; t < NT; ++t) {
    const int cur = t & 1;
    if (t + 1 < NT) {
      // write tile t+1 (in regs) into buf[cur^1]; overlaps with compute below
      char* kw = (char*)&Ks[cur ^ 1][sr][0];
      char* vw = (char*)&Vs[cur ^ 1][sr][0];
      *(us8*)(kw + ((scb +  0) ^ ssw)) = rk0;
      *(us8*)(kw + ((scb + 16) ^ ssw)) = rk1;
      *(us8*)(vw + ((scb +  0) ^ ssw)) = rv0;
      *(us8*)(vw + ((scb + 16) ^ ssw)) = rv1;
      if (t + 2 < NT) {              // prefetch tile t+2 into regs
        const size_t ko = (size_t)(t + 2) * 64;
        rk0 = *(const us8*)(pK + ko * DMODEL);
        rk1 = *(const us8*)(pK + ko * DMODEL + 8);
        rv0 = *(const us8*)(pV + ko);
        rv1 = *(const us8*)(pV + ko + 8);
      }
    }

    // ---- S^T tile for both q-subtiles: each kf read feeds 2 MFMAs ----
    f32x4 sA[4], sB[4];
#pragma unroll
    for (int mt = 0; mt < 4; ++mt)
#pragma unroll
      for (int r = 0; r < 4; ++r) { sA[mt][r] = 0.f; sB[mt][r] = 0.f; }
    __builtin_amdgcn_s_setprio(1);
#pragma unroll
    for (int mt = 0; mt < 4; ++mt) {
      char* kr = (char*)&Ks[cur][mt * 16 + ml][0];
      bf16x8 kf0 = *(const bf16x8*)(kr + (((quad << 4) +  0) ^ fsw));
      bf16x8 kf1 = *(const bf16x8*)(kr + (((quad << 4) + 64) ^ fsw));
      sA[mt] = __builtin_amdgcn_mfma_f32_16x16x32_bf16(kf0, qfA0, sA[mt], 0, 0, 0);
      sA[mt] = __builtin_amdgcn_mfma_f32_16x16x32_bf16(kf1, qfA1, sA[mt], 0, 0, 0);
      sB[mt] = __builtin_amdgcn_mfma_f32_16x16x32_bf16(kf0, qfB0, sB[mt], 0, 0, 0);
      sB[mt] = __builtin_amdgcn_mfma_f32_16x16x32_bf16(kf1, qfB1, sB[mt], 0, 0, 0);
    }
    __builtin_amdgcn_s_setprio(0);

    // ---- V fragments hoisted to regs (read once, used by PV-A and PV-B) ----
    bf16x8 vf[4][2];
#pragma unroll
    for (int dt = 0; dt < 4; ++dt) {
      char* vr = (char*)&Vs[cur][dt * 16 + ml][0];
      vf[dt][0] = *(const bf16x8*)(vr + (((quad << 4) +  0) ^ fsw));
      vf[dt][1] = *(const bf16x8*)(vr + (((quad << 4) + 64) ^ fsw));
    }

    // ---- subtile A: exp, pack P^T -> QP, PV-A ----
#pragma unroll
    for (int mt = 0; mt < 4; ++mt) {
      float e0 = exp2f(sA[mt][0] * SCL2E), e1 = exp2f(sA[mt][1] * SCL2E),
            e2 = exp2f(sA[mt][2] * SCL2E), e3 = exp2f(sA[mt][3] * SCL2E);
      lsumA += (e0 + e1) + (e2 + e3);
      ushort4 oA;
      oA.x = f2bfu(e0); oA.y = f2bfu(e1); oA.z = f2bfu(e2); oA.w = f2bfu(e3);
      *(ushort4*)(qp + (((mt << 5) + (quad << 3)) ^ fsw)) = oA;
    }
    {
      bf16x8 pf0 = *(const bf16x8*)(qp + (((quad << 4) +  0) ^ fsw));
      bf16x8 pf1 = *(const bf16x8*)(qp + (((quad << 4) + 64) ^ fsw));
      __builtin_amdgcn_s_setprio(1);
#pragma unroll
      for (int dt = 0; dt < 4; ++dt) {
        oaccA[dt] = __builtin_amdgcn_mfma_f32_16x16x32_bf16(vf[dt][0], pf0, oaccA[dt], 0, 0, 0);
        oaccA[dt] = __builtin_amdgcn_mfma_f32_16x16x32_bf16(vf[dt][1], pf1, oaccA[dt], 0, 0, 0);
      }
      __builtin_amdgcn_s_setprio(0);
    }

    // ---- subtile B: exp, pack P^T -> QP (overwrite), PV-B ----
#pragma unroll
    for (int mt = 0; mt < 4; ++mt) {
      float e0 = exp2f(sB[mt][0] * SCL2E), e1 = exp2f(sB[mt][1] * SCL2E),
            e2 = exp2f(sB[mt][2] * SCL2E), e3 = exp2f(sB[mt][3] * SCL2E);
      lsumB += (e0 + e1) + (e2 + e3);
      ushort4 oB;
      oB.x = f2bfu(e0); oB.y = f2bfu(e1); oB.z = f2bfu(e2); oB.w = f2bfu(e3);
      *(ushort4*)(qp + (((mt << 5) + (quad << 3)) ^ fsw)) = oB;
    }
    {
      bf16x8 pf0 = *(const bf16x8*)(qp + (((quad << 4) +  0) ^ fsw));
      bf16x8 pf1 = *(const bf16x8*)(qp + (((quad << 4) + 64) ^ fsw));
      __builtin_amdgcn_s_setprio(1);
#pragma unroll
      for (int dt = 0; dt < 4; ++dt) {
        oaccB[dt] = __builtin_amdgcn_mfma_f32_16x16x32_bf16(vf[dt][0], pf0, oaccB[dt], 0, 0, 0);
        oaccB[dt] = __builtin_amdgcn_mfma_f32_16x16x32_bf16(vf[dt][1], pf1, oaccB[dt], 0, 0, 0);
      }
      __builtin_amdgcn_s_setprio(0);
    }

    __syncthreads();   // readers of buf[cur] done; writes of buf[nxt] visible
  }

  // ---- cross-quad l reduction (lanes with same ml share q) ----
  lsumA += __shfl_xor(lsumA, 16);
  lsumA += __shfl_xor(lsumA, 32);
  lsumB += __shfl_xor(lsumB, 16);
  lsumB += __shfl_xor(lsumB, 32);
  const size_t lbase = (((size_t)(ks * 2 + b)) * NHEAD + h) * S_LEN;
  const size_t obaseA = (lbase + qrA) * DKH;
  const size_t obaseB = (lbase + qrB) * DKH;
#pragma unroll
  for (int dt = 0; dt < 4; ++dt) {
    *(f32x4*)&Opart[obaseA + dt * 16 + (quad << 2)] = oaccA[dt];
    *(f32x4*)&Opart[obaseB + dt * 16 + (quad << 2)] = oaccB[dt];
  }
  if (quad == 0) {
    Lpart[lbase + qrA] = lsumA;
    Lpart[lbase + qrB] = lsumB;
  }
}

// ---------------------------------------------------------------------------
// combine split-K attention partials: O = (O0+O1)/(l0+l1), bf16 [B][S][H*DKH]
// ---------------------------------------------------------------------------
__global__ __launch_bounds__(256) void attn_combine_kernel(
    const float* __restrict__ Op,   // [KSPLIT][B][H][S][DKH]
    const float* __restrict__ Lp,   // [KSPLIT][B][H][S]
    unsigned short* __restrict__ O) // [B][S][DMODEL]
{
  const int s = blockIdx.x & (S_LEN - 1);
  const int b = blockIdx.x >> 11;
  const int tid = threadIdx.x;
  const size_t ohalf = (size_t)2 * NHEAD * S_LEN * DKH;
  const size_t lhalf = (size_t)2 * NHEAD * S_LEN;
#pragma unroll
  for (int c = tid; c < DMODEL; c += 256) {
    const int hh = c >> 6, dd = c & 63;
    const size_t li = ((size_t)b * NHEAD + hh) * S_LEN + s;
    const size_t oi = li * DKH + dd;
    const float o = Op[oi] + Op[ohalf + oi];
    const float l = Lp[li] + Lp[lhalf + li];
    O[((size_t)b * S_LEN + s) * DMODEL + c] = f2bfu(o / l);
  }
}

// ---------------------------------------------------------------------------
// out = LayerNorm(X + Y [+ Y2]) * w + b; dtype flags (1 = bf16); Y2 nullable
// ---------------------------------------------------------------------------
__global__ __launch_bounds__(256) void add_ln_kernel(
    const void* __restrict__ X, const void* __restrict__ Y,
    const void* __restrict__ Y2,
    const float* __restrict__ w, const float* __restrict__ bvec,
    void* __restrict__ out, int xbf, int ybf, int obf)
{
  __shared__ float buf[DMODEL];
  __shared__ float rbuf[8];
  const int tid  = threadIdx.x;
  const int lane = tid & 63, wv = tid >> 6;
  const size_t base = (size_t)blockIdx.x * DMODEL;

  float s = 0.f, s2 = 0.f;
#pragma unroll
  for (int j = tid; j < DMODEL; j += 256) {
    float xv = xbf ? bfu2f(((const unsigned short*)X)[base + j])
                   : ((const float*)X)[base + j];
    float yv = ybf ? bfu2f(((const unsigned short*)Y)[base + j])
                   : ((const float*)Y)[base + j];
    float v = xv + yv;
    if (Y2) v += ybf ? bfu2f(((const unsigned short*)Y2)[base + j])
                     : ((const float*)Y2)[base + j];
    buf[j] = v; s += v; s2 += v * v;
  }
#pragma unroll
  for (int o = 32; o; o >>= 1) { s += __shfl_xor(s, o); s2 += __shfl_xor(s2, o); }
  if (lane == 0) { rbuf[wv] = s; rbuf[4 + wv] = s2; }
  __syncthreads();
  const float S  = rbuf[0] + rbuf[1] + rbuf[2] + rbuf[3];
  const float S2 = rbuf[4] + rbuf[5] + rbuf[6] + rbuf[7];
  const float mean = S * (1.f / (float)DMODEL);
  const float var  = S2 * (1.f / (float)DMODEL) - mean * mean;
  const float rstd = rsqrtf(var + 1e-5f);
#pragma unroll
  for (int j = tid; j < DMODEL; j += 256) {
    float v = (buf[j] - mean) * rstd * w[j] + bvec[j];
    if (obf) ((unsigned short*)out)[base + j] = f2bfu(v);
    else     ((float*)out)[base + j] = v;
  }
}

// ---------------------------------------------------------------------------
extern "C" void kernel_launch(void* const* d_in, const int* in_sizes, int n_in,
                              void* d_out, int out_size, void* d_ws, size_t ws_size,
                              hipStream_t stream) {
  const float* src  = (const float*)d_in[0];
  const float* Wq   = (const float*)d_in[1];
  const float* bq   = (const float*)d_in[2];
  const float* Wk   = (const float*)d_in[3];
  const float* bk   = (const float*)d_in[4];
  const float* Wv   = (const float*)d_in[5];
  const float* bv   = (const float*)d_in[6];
  const float* Wo   = (const float*)d_in[7];
  const float* bo   = (const float*)d_in[8];
  const float* ln1w = (const float*)d_in[9];
  const float* ln1b = (const float*)d_in[10];
  const float* W1   = (const float*)d_in[11];
  const float* b1   = (const float*)d_in[12];
  const float* W2   = (const float*)d_in[13];
  const float* b2   = (const float*)d_in[14];
  const float* ln2w = (const float*)d_in[15];
  const float* ln2b = (const float*)d_in[16];
  (void)ws_size; (void)in_sizes; (void)n_in; (void)out_size;

  unsigned short* p = (unsigned short*)d_ws;
  const size_t SEG = (size_t)MROWS * DMODEL;
  unsigned short* srcb = p; p += SEG;
  unsigned short* qb   = p; p += SEG;   // Q; later split-K partial z0
  unsigned short* kb_  = p; p += SEG;   // K; later x1
  unsigned short* vbT  = p; p += SEG;   // V^T; later split-K partial z1
  unsigned short* ctx  = p; p += SEG;
  unsigned short* ff   = p; p += (size_t)MROWS * DFF_K;
  unsigned short* wqt  = p; p += (size_t)DMODEL * DMODEL;
  unsigned short* wkt  = p; p += (size_t)DMODEL * DMODEL;
  unsigned short* wvt  = p; p += (size_t)DMODEL * DMODEL;
  unsigned short* wot  = p; p += (size_t)DMODEL * DMODEL;
  unsigned short* w1t  = p; p += (size_t)DMODEL * DFF_K;
  unsigned short* w2t  = p; p += (size_t)DMODEL * DFF_K;
  unsigned short* x1 = kb_;
  // attention split-K scratch (regions dead during attention):
  //   ff  (25.17 MB) exactly fits [KSPLIT][B][H][S][DKH] f32 O-partials
  //   wqt (1.18 MB)  holds [KSPLIT][B][H][S] f32 l-partials (393 KB)
  float* opart = (float*)ff;
  float* lpart = (float*)wqt;

  dim3 blk(256);

  // 0: conversions
  convert_kernel<<<dim3(SEG / 1024), blk, 0, stream>>>(src, srcb, (int)(SEG / 4));
  transpose_conv4_kernel<<<dim3(12, 12, 4), blk, 0, stream>>>(
      Wq, Wk, Wv, Wo, wqt, wkt, wvt, wot);
  transpose_conv_kernel<<<dim3(12, 48), blk, 0, stream>>>(W1, w1t, DMODEL, DFF_K, 0);
  transpose_conv_kernel<<<dim3(48, 12), blk, 0, stream>>>(W2, w2t, DFF_K, DMODEL, 0);

  // 1: fused QKV projections (BN=64, 1152 blocks; V written transposed)
  dim3 gqkv(MROWS / 128, DMODEL / 64, 3);      // 32 x 12 x 3
  qkv_gemm_kernel<<<gqkv, blk, 0, stream>>>(srcb, wqt, wkt, wvt, bq, bk, bv,
                                            qb, kb_, vbT);

  // 2: MFMA flash attention v6 (40KB LDS, 4 blocks/CU) -> f32 partials
  dim3 ga(NHEAD, 2, (S_LEN / 128) * KSPLIT);   // 12 x 2 x 32 = 768 blocks
  flash_attn_mfma<<<ga, blk, 0, stream>>>(qb, kb_, vbT, opart, lpart);
  attn_combine_kernel<<<dim3(MROWS), blk, 0, stream>>>(opart, lpart, ctx);

  // 3: attn_out partials = ctx @ Wo + bo, BN=64 split-K=2 -> qb (z0), vbT (z1)
  dim3 gWo(MROWS / 128, DMODEL / 64, 2);       // 32 x 12 x 2 = 768
  mfma_gemm_kernel<64><<<gWo, blk, 0, stream>>>(ctx, wot, bo, qb,
                                                DMODEL, DMODEL, 0, DMODEL / 2, 2 * SEG);

  // 4: x1 = LN(srcb + p0 + p1)
  add_ln_kernel<<<dim3(MROWS), blk, 0, stream>>>(srcb, qb, vbT,
                                                 ln1w, ln1b, x1, 1, 1, 1);

  // 5: ff = relu(x1 @ W1 + b1)  (BN=128, 768 blocks)
  dim3 gF1(MROWS / 128, DFF_K / 128, 1);       // 32 x 24
  mfma_gemm_kernel<128><<<gF1, blk, 0, stream>>>(x1, w1t, b1, ff,
                                                 DMODEL, DFF_K, 1, DMODEL, 0);

  // 6: y2 partials = ff @ W2 + b2, BN=64 split-K=2 -> qb (z0), vbT (z1)
  dim3 gW2(MROWS / 128, DMODEL / 64, 2);       // 32 x 12 x 2 = 768
  mfma_gemm_kernel<64><<<gW2, blk, 0, stream>>>(ff, w2t, b2, qb,
                                                DFF_K, DMODEL, 0, DFF_K / 2, 2 * SEG);

  // 7: out = LN(x1 + p0 + p1)
  add_ln_kernel<<<dim3(MROWS), blk, 0, stream>>>(x1, qb, vbT,
                                                 ln2w, ln2b, (float*)d_out, 1, 1, 0);
}

// Round 11
// 287.645 us; speedup vs baseline: 1.3364x; 1.3364x over previous
//
#include <hip/hip_runtime.h>
#include <hip/hip_bf16.h>

#define S_LEN 2048
#define DMODEL 768
#define NHEAD 12
#define DKH 64
#define DFF_K 3072
#define MROWS 4096   // B*S
#define KSPLIT 2
#define KHALF (S_LEN / KSPLIT)

typedef __attribute__((ext_vector_type(8))) short bf16x8;
typedef __attribute__((ext_vector_type(8))) unsigned short us8;
typedef __attribute__((ext_vector_type(4))) float f32x4;

__device__ __forceinline__ float bfu2f(unsigned short u) {
  return __uint_as_float(((unsigned int)u) << 16);
}
__device__ __forceinline__ unsigned short f2bfu(float f) {
  __hip_bfloat16 h = __float2bfloat16(f);
  return *reinterpret_cast<unsigned short*>(&h);
}

// async global->LDS 16B: LDS dest is wave-uniform base + lane*16 (HW rule)
__device__ __forceinline__ void async16(const unsigned short* g, unsigned short* l) {
  __builtin_amdgcn_global_load_lds(
      (const __attribute__((address_space(1))) unsigned int*)g,
      (__attribute__((address_space(3))) unsigned int*)l, 16, 0, 0);
}

// ---------------------------------------------------------------------------
// fp32 -> bf16 elementwise convert
// ---------------------------------------------------------------------------
__global__ __launch_bounds__(256) void convert_kernel(
    const float* __restrict__ in, unsigned short* __restrict__ out, int n4)
{
  const int i = blockIdx.x * 256 + threadIdx.x;
  if (i < n4) {
    float4 v = *(const float4*)(in + (size_t)i * 4);
    ushort4 o;
    o.x = f2bfu(v.x); o.y = f2bfu(v.y); o.z = f2bfu(v.z); o.w = f2bfu(v.w);
    *(ushort4*)(out + (size_t)i * 4) = o;
  }
}

// ---------------------------------------------------------------------------
// fp32 [R][C] -> bf16 [C][R] transpose-convert (generic, head or flat).
// ---------------------------------------------------------------------------
__device__ __forceinline__ void transpose_conv_body(
    const float* in, unsigned short* out, int R, int Ctot, int head,
    int bx, int by, int tid)
{
  __shared__ float t[64][68];
  const int r0 = bx * 64;
  const int c0 = by * 64;
  const float* ib;
  int ld;
  if (head) { ib = in + (size_t)by * R * 64; ld = 64; }
  else      { ib = in + c0;                  ld = Ctot; }
  const int lr = tid >> 4;
  const int lc = (tid & 15) << 2;

#pragma unroll
  for (int rr = 0; rr < 4; ++rr) {
    const int row = rr * 16 + lr;
    float4 v = *(const float4*)(ib + (size_t)(r0 + row) * ld + lc);
    t[row][lc + 0] = v.x; t[row][lc + 1] = v.y;
    t[row][lc + 2] = v.z; t[row][lc + 3] = v.w;
  }
  __syncthreads();
#pragma unroll
  for (int rr = 0; rr < 4; ++rr) {
    const int oc = rr * 16 + lr;
    ushort4 o;
    o.x = f2bfu(t[lc + 0][oc]); o.y = f2bfu(t[lc + 1][oc]);
    o.z = f2bfu(t[lc + 2][oc]); o.w = f2bfu(t[lc + 3][oc]);
    *(ushort4*)(out + (size_t)(c0 + oc) * R + r0 + lc) = o;
  }
}

__global__ __launch_bounds__(256) void transpose_conv_kernel(
    const float* __restrict__ in, unsigned short* __restrict__ out,
    int R, int Ctot, int head)
{
  transpose_conv_body(in, out, R, Ctot, head, blockIdx.x, blockIdx.y, threadIdx.x);
}

// fused Wq/Wk/Wv/Wo transpose: z selects tensor; z<3 head-mode
__global__ __launch_bounds__(256) void transpose_conv4_kernel(
    const float* __restrict__ i0, const float* __restrict__ i1,
    const float* __restrict__ i2, const float* __restrict__ i3,
    unsigned short* __restrict__ o0, unsigned short* __restrict__ o1,
    unsigned short* __restrict__ o2, unsigned short* __restrict__ o3)
{
  const int z = blockIdx.z;
  const float* in = (z == 0) ? i0 : (z == 1) ? i1 : (z == 2) ? i2 : i3;
  unsigned short* out = (z == 0) ? o0 : (z == 1) ? o1 : (z == 2) ? o2 : o3;
  transpose_conv_body(in, out, DMODEL, DMODEL, (z < 3) ? 1 : 0,
                      blockIdx.x, blockIdx.y, threadIdx.x);
}

// ---------------------------------------------------------------------------
// Stage one BK=64 tile pair (A: 128 rows, B: BN rows, 64 cols bf16) into
// linear LDS via global_load_lds width-16. Global source is inverse-XOR-
// swizzled (slot ^= row&7) so that swizzled ds_reads see linear data.
// Per-thread instruction count: 4 + BN/32 (6 for BN=64, 8 for BN=128).
// ---------------------------------------------------------------------------
template<int BN>
__device__ __forceinline__ void stage_tile(
    const unsigned short* __restrict__ Ab,   // A + row0*K (+0), element ptr
    const unsigned short* __restrict__ Bb,   // BT + col0*K
    unsigned short* As, unsigned short* Bs,  // LDS linear [rows][64]
    int wid, int lane, int K, int kofs)      // kofs in elements
{
  const int r = lane >> 3;
  const int s = lane & 7;
#pragma unroll
  for (int p = 0; p < 4; ++p) {
    const int row = wid * 32 + p * 8 + r;
    async16(Ab + (size_t)row * K + kofs + ((s ^ (row & 7)) << 3),
            As + (size_t)(wid * 32 + p * 8) * 64);
  }
#pragma unroll
  for (int p = 0; p < BN / 32; ++p) {
    const int row = wid * (BN / 4) + p * 8 + r;
    async16(Bb + (size_t)row * K + kofs + ((s ^ (row & 7)) << 3),
            Bs + (size_t)(wid * (BN / 4) + p * 8) * 64);
  }
}

// ---------------------------------------------------------------------------
// MFMA bf16 GEMM, BK=64, double-buffered LDS filled by global_load_lds,
// XOR-swizzled reads, COUNTED-vmcnt pipeline: next tile's stage loads stay
// in flight across both barriers (proven round-5 structure).
// C = act(A[M x K] @ BT[N x K]^T + bias). BM=128, BN template (64 or 128).
// Grid: x = M row-block, y = N col-block, z = K-split
// (partial z -> C + z*out_stride; bias from z==0 only).
// ---------------------------------------------------------------------------
template<int BN>
__global__ __launch_bounds__(256) void mfma_gemm_kernel(
    const unsigned short* __restrict__ A,
    const unsigned short* __restrict__ BT,
    const float* __restrict__ bias,
    unsigned short* __restrict__ C,
    int K, int N, int relu, int klen, size_t out_stride)
{
  constexpr int WN = (BN == 128) ? 64 : 32;
  constexpr int NJ = WN / 16;
  __shared__ unsigned short As[2][128][64];
  __shared__ unsigned short Bs[2][BN][64];

  const int tid  = threadIdx.x;
  const int wid  = tid >> 6;
  const int lane = tid & 63;
  const int ml   = lane & 15;
  const int quad = lane >> 4;
  const int wm   = (wid & 1) * 64;
  const int wn   = (wid >> 1) * WN;
  const int row0 = blockIdx.x * 128;
  const int col0 = blockIdx.y * BN;
  const int zed  = blockIdx.z;
  const int kb0  = zed * klen;
  const int nsteps = klen >> 6;
  const int fsw = (ml & 7) << 4;   // fragment-read swizzle (row&7 == ml&7)

  const unsigned short* Ab = A  + (size_t)row0 * K + kb0;
  const unsigned short* Bb = BT + (size_t)col0 * K + kb0;

  f32x4 acc[4][NJ];
#pragma unroll
  for (int i = 0; i < 4; ++i)
#pragma unroll
    for (int j = 0; j < NJ; ++j)
#pragma unroll
      for (int r = 0; r < 4; ++r) acc[i][j][r] = 0.f;

  stage_tile<BN>(Ab, Bb, &As[0][0][0], &Bs[0][0][0], wid, lane, K, 0);

  for (int st = 0; st < nsteps; ++st) {
    const int cur = st & 1;
    if (st + 1 < nsteps) {
      stage_tile<BN>(Ab, Bb, &As[cur ^ 1][0][0], &Bs[cur ^ 1][0][0],
                     wid, lane, K, (st + 1) << 6);
      if constexpr (BN == 128) { asm volatile("s_waitcnt vmcnt(8)" ::: "memory"); }
      else                     { asm volatile("s_waitcnt vmcnt(6)" ::: "memory"); }
    } else {
      asm volatile("s_waitcnt vmcnt(0)" ::: "memory");
    }
    __builtin_amdgcn_s_barrier();   // all waves: stage(t) landed in LDS

    const char* Ac = (const char*)&As[cur][0][0];
    const char* Bc = (const char*)&Bs[cur][0][0];
#pragma unroll
    for (int h = 0; h < 2; ++h) {
      bf16x8 af[4], bfr[NJ];
#pragma unroll
      for (int i = 0; i < 4; ++i) {
        const int ar = wm + i * 16 + ml;
        af[i] = *(const bf16x8*)(Ac + ar * 128 + (((h << 6) + (quad << 4)) ^ fsw));
      }
#pragma unroll
      for (int j = 0; j < NJ; ++j) {
        const int br = wn + j * 16 + ml;
        bfr[j] = *(const bf16x8*)(Bc + br * 128 + (((h << 6) + (quad << 4)) ^ fsw));
      }
#pragma unroll
      for (int i = 0; i < 4; ++i)
#pragma unroll
        for (int j = 0; j < NJ; ++j)
          acc[i][j] = __builtin_amdgcn_mfma_f32_16x16x32_bf16(
              af[i], bfr[j], acc[i][j], 0, 0, 0);
    }
    __builtin_amdgcn_s_barrier();   // readers of buf[cur] done
  }

  unsigned short* Cz = C + (size_t)zed * out_stride;
#pragma unroll
  for (int j = 0; j < NJ; ++j) {
    const int col = col0 + wn + j * 16 + ml;
    const float bb = (zed == 0) ? bias[col] : 0.f;
#pragma unroll
    for (int i = 0; i < 4; ++i) {
      const int r0g = row0 + wm + i * 16 + (quad << 2);
#pragma unroll
      for (int r = 0; r < 4; ++r) {
        float v = acc[i][j][r] + bb;
        if (relu) v = fmaxf(v, 0.f);
        Cz[(size_t)(r0g + r) * N + col] = f2bfu(v);
      }
    }
  }
}

// fused QKV projection (per-z, 1152 blocks): z=0 -> Q, z=1 -> K, z=2 -> V
// (VT store). BN=64, BK=64 gload_lds staging + counted vmcnt.
__global__ __launch_bounds__(256) void qkv_gemm_kernel(
    const unsigned short* __restrict__ A,
    const unsigned short* __restrict__ W0, const unsigned short* __restrict__ W1,
    const unsigned short* __restrict__ W2,
    const float* __restrict__ bq, const float* __restrict__ bk,
    const float* __restrict__ bv,
    unsigned short* __restrict__ C0, unsigned short* __restrict__ C1,
    unsigned short* __restrict__ C2)
{
  __shared__ unsigned short As[2][128][64];
  __shared__ unsigned short Bs[2][64][64];
  const int z = blockIdx.z;
  const unsigned short* BT = (z == 0) ? W0 : (z == 1) ? W1 : W2;
  const float* bias = (z == 0) ? bq : (z == 1) ? bk : bv;
  unsigned short* C = (z == 0) ? C0 : (z == 1) ? C1 : C2;
  const int K = DMODEL, N = DMODEL;

  const int tid  = threadIdx.x;
  const int wid  = tid >> 6;
  const int lane = tid & 63;
  const int ml   = lane & 15;
  const int quad = lane >> 4;
  const int wm   = (wid & 1) * 64;
  const int wn   = (wid >> 1) * 32;
  const int row0 = blockIdx.x * 128;
  const int col0 = blockIdx.y * 64;
  const int fsw = (ml & 7) << 4;

  const unsigned short* Ab = A  + (size_t)row0 * K;
  const unsigned short* Bb = BT + (size_t)col0 * K;

  f32x4 acc[4][2];
#pragma unroll
  for (int i = 0; i < 4; ++i)
#pragma unroll
    for (int j = 0; j < 2; ++j)
#pragma unroll
      for (int r = 0; r < 4; ++r) acc[i][j][r] = 0.f;

  stage_tile<64>(Ab, Bb, &As[0][0][0], &Bs[0][0][0], wid, lane, K, 0);

  const int nsteps = K >> 6;   // 12
  for (int st = 0; st < nsteps; ++st) {
    const int cur = st & 1;
    if (st + 1 < nsteps) {
      stage_tile<64>(Ab, Bb, &As[cur ^ 1][0][0], &Bs[cur ^ 1][0][0],
                     wid, lane, K, (st + 1) << 6);
      asm volatile("s_waitcnt vmcnt(6)" ::: "memory");
    } else {
      asm volatile("s_waitcnt vmcnt(0)" ::: "memory");
    }
    __builtin_amdgcn_s_barrier();

    const char* Ac = (const char*)&As[cur][0][0];
    const char* Bc = (const char*)&Bs[cur][0][0];
#pragma unroll
    for (int h = 0; h < 2; ++h) {
      bf16x8 af[4], bfr[2];
#pragma unroll
      for (int i = 0; i < 4; ++i) {
        const int ar = wm + i * 16 + ml;
        af[i] = *(const bf16x8*)(Ac + ar * 128 + (((h << 6) + (quad << 4)) ^ fsw));
      }
#pragma unroll
      for (int j = 0; j < 2; ++j) {
        const int br = wn + j * 16 + ml;
        bfr[j] = *(const bf16x8*)(Bc + br * 128 + (((h << 6) + (quad << 4)) ^ fsw));
      }
#pragma unroll
      for (int i = 0; i < 4; ++i)
#pragma unroll
        for (int j = 0; j < 2; ++j)
          acc[i][j] = __builtin_amdgcn_mfma_f32_16x16x32_bf16(
              af[i], bfr[j], acc[i][j], 0, 0, 0);
    }
    __builtin_amdgcn_s_barrier();
  }

#pragma unroll
  for (int j = 0; j < 2; ++j) {
    const int col = col0 + wn + j * 16 + ml;
    const float bb = bias[col];
#pragma unroll
    for (int i = 0; i < 4; ++i) {
      const int r0g = row0 + wm + i * 16 + (quad << 2);
      if (z == 2) {
        const int bb_ = r0g >> 11, s = r0g & 2047;
        const int hh = col >> 6, dd = col & 63;
        ushort4 o;
        o.x = f2bfu(acc[i][j][0] + bb); o.y = f2bfu(acc[i][j][1] + bb);
        o.z = f2bfu(acc[i][j][2] + bb); o.w = f2bfu(acc[i][j][3] + bb);
        *(ushort4*)(C + ((size_t)((bb_ * NHEAD + hh) * DKH + dd)) * S_LEN + s) = o;
      } else {
#pragma unroll
        for (int r = 0; r < 4; ++r)
          C[(size_t)(r0g + r) * N + col] = f2bfu(acc[i][j][r] + bb);
      }
    }
  }
}

// ---------------------------------------------------------------------------
// MFMA flash attention v6b: v4 structure (proven 53.3us, 76 VGPR at
// launch_bounds(256,3)) with ONLY the QP buffer halved to 8KB: PV runs
// A-then-B through one per-wave P^T buffer, V fragments re-read from LDS
// per subtile (NO vf hoist -- v6's hoist + launch_bounds(256,4) spilled:
// VGPR 64, 254MB scratch FETCH, 150us). LDS 40KB -> 4 blocks/CU by LDS
// limit alone; launch_bounds kept at (256,3) so regalloc matches v4.
// Grid: x = head, y = batch, z = qtile128*KSPLIT + split.
// ---------------------------------------------------------------------------
#define SCL2E 0.1803368822f   // 0.125 * log2(e)
__global__ __launch_bounds__(256, 3) void flash_attn_mfma(
    const unsigned short* __restrict__ Q,
    const unsigned short* __restrict__ K,
    const unsigned short* __restrict__ VT,
    float* __restrict__ Opart,      // [KSPLIT][B][H][S][DKH] f32, unnormalized
    float* __restrict__ Lpart)      // [KSPLIT][B][H][S] f32
{
  __shared__ unsigned short Ks[2][64][64];     // 16 KB
  __shared__ unsigned short Vs[2][64][64];     // 16 KB  (VT tile: [d][t])
  __shared__ unsigned short QP[4][16][64];     //  8 KB  per-wave P^T (A then B)

  const int tid  = threadIdx.x;
  const int wid  = tid >> 6;
  const int lane = tid & 63;
  const int ml   = lane & 15;
  const int quad = lane >> 4;
  const int h    = blockIdx.x, b = blockIdx.y;
  const int q0   = (blockIdx.z >> 1) * 128;
  const int ks   = blockIdx.z & 1;
  const int kt0  = ks * KHALF;

  const size_t qkbase = ((size_t)b * S_LEN) * DMODEL + (size_t)h * DKH;
  const size_t vtbase = ((size_t)(b * NHEAD + h)) * DKH * S_LEN;

  const int sr  = tid >> 2;          // 0..63 staging row
  const int scb = (tid & 3) << 5;    // staging byte col: 0,32,64,96
  const int ssw = (sr & 7) << 4;     // staging swizzle
  const int fsw = (ml & 7) << 4;     // fragment-row swizzle (row&7 == ml&7)

  // ---- Q fragments direct from global (once per block) ----
  const int qrA = q0 + wid * 32 + ml;
  const int qrB = qrA + 16;
  const unsigned short* qpg = Q + qkbase;
  bf16x8 qfA0 = *(const bf16x8*)(qpg + (size_t)qrA * DMODEL + (quad << 3));
  bf16x8 qfA1 = *(const bf16x8*)(qpg + (size_t)qrA * DMODEL + 32 + (quad << 3));
  bf16x8 qfB0 = *(const bf16x8*)(qpg + (size_t)qrB * DMODEL + (quad << 3));
  bf16x8 qfB1 = *(const bf16x8*)(qpg + (size_t)qrB * DMODEL + 32 + (quad << 3));

  const unsigned short* pK = K + qkbase + (size_t)(kt0 + sr) * DMODEL + (scb >> 1);
  const unsigned short* pV = VT + vtbase + (size_t)sr * S_LEN + kt0 + (scb >> 1);

  float lsumA = 0.f, lsumB = 0.f;
  f32x4 oaccA[4], oaccB[4];
#pragma unroll
  for (int dt = 0; dt < 4; ++dt)
#pragma unroll
    for (int r = 0; r < 4; ++r) { oaccA[dt][r] = 0.f; oaccB[dt][r] = 0.f; }

  char* qp = (char*)&QP[wid][ml][0];

  // ---- prologue: tile0 -> regs -> buf0; tile1 -> regs; barrier ----
  us8 rk0 = *(const us8*)(pK);
  us8 rk1 = *(const us8*)(pK + 8);
  us8 rv0 = *(const us8*)(pV);
  us8 rv1 = *(const us8*)(pV + 8);
  {
    char* kw = (char*)&Ks[0][sr][0];
    char* vw = (char*)&Vs[0][sr][0];
    *(us8*)(kw + ((scb +  0) ^ ssw)) = rk0;
    *(us8*)(kw + ((scb + 16) ^ ssw)) = rk1;
    *(us8*)(vw + ((scb +  0) ^ ssw)) = rv0;
    *(us8*)(vw + ((scb + 16) ^ ssw)) = rv1;
  }
  rk0 = *(const us8*)(pK + (size_t)64 * DMODEL);
  rk1 = *(const us8*)(pK + (size_t)64 * DMODEL + 8);
  rv0 = *(const us8*)(pV + 64);
  rv1 = *(const us8*)(pV + 64 + 8);
  __syncthreads();

  const int NT = KHALF / 64;   // 16
  for (int t = 0; t < NT; ++t) {
    const int cur = t & 1;
    if (t + 1 < NT) {
      // write tile t+1 (in regs) into buf[cur^1]; overlaps with compute below
      char* kw = (char*)&Ks[cur ^ 1][sr][0];
      char* vw = (char*)&Vs[cur ^ 1][sr][0];
      *(us8*)(kw + ((scb +  0) ^ ssw)) = rk0;
      *(us8*)(kw + ((scb + 16) ^ ssw)) = rk1;
      *(us8*)(vw + ((scb +  0) ^ ssw)) = rv0;
      *(us8*)(vw + ((scb + 16) ^ ssw)) = rv1;
      if (t + 2 < NT) {              // prefetch tile t+2 into regs
        const size_t ko = (size_t)(t + 2) * 64;
        rk0 = *(const us8*)(pK + ko * DMODEL);
        rk1 = *(const us8*)(pK + ko * DMODEL + 8);
        rv0 = *(const us8*)(pV + ko);
        rv1 = *(const us8*)(pV + ko + 8);
      }
    }

    // ---- S^T tile for both q-subtiles: each kf read feeds 2 MFMAs ----
    f32x4 sA[4], sB[4];
#pragma unroll
    for (int mt = 0; mt < 4; ++mt)
#pragma unroll
      for (int r = 0; r < 4; ++r) { sA[mt][r] = 0.f; sB[mt][r] = 0.f; }
    __builtin_amdgcn_s_setprio(1);
#pragma unroll
    for (int mt = 0; mt < 4; ++mt) {
      char* kr = (char*)&Ks[cur][mt * 16 + ml][0];
      bf16x8 kf0 = *(const bf16x8*)(kr + (((quad << 4) +  0) ^ fsw));
      bf16x8 kf1 = *(const bf16x8*)(kr + (((quad << 4) + 64) ^ fsw));
      sA[mt] = __builtin_amdgcn_mfma_f32_16x16x32_bf16(kf0, qfA0, sA[mt], 0, 0, 0);
      sA[mt] = __builtin_amdgcn_mfma_f32_16x16x32_bf16(kf1, qfA1, sA[mt], 0, 0, 0);
      sB[mt] = __builtin_amdgcn_mfma_f32_16x16x32_bf16(kf0, qfB0, sB[mt], 0, 0, 0);
      sB[mt] = __builtin_amdgcn_mfma_f32_16x16x32_bf16(kf1, qfB1, sB[mt], 0, 0, 0);
    }
    __builtin_amdgcn_s_setprio(0);

    // ---- subtile A: exp, pack P^T -> QP, PV-A (vf read from LDS) ----
#pragma unroll
    for (int mt = 0; mt < 4; ++mt) {
      float e0 = exp2f(sA[mt][0] * SCL2E), e1 = exp2f(sA[mt][1] * SCL2E),
            e2 = exp2f(sA[mt][2] * SCL2E), e3 = exp2f(sA[mt][3] * SCL2E);
      lsumA += (e0 + e1) + (e2 + e3);
      ushort4 oA;
      oA.x = f2bfu(e0); oA.y = f2bfu(e1); oA.z = f2bfu(e2); oA.w = f2bfu(e3);
      *(ushort4*)(qp + (((mt << 5) + (quad << 3)) ^ fsw)) = oA;
    }
    {
      bf16x8 pf0 = *(const bf16x8*)(qp + (((quad << 4) +  0) ^ fsw));
      bf16x8 pf1 = *(const bf16x8*)(qp + (((quad << 4) + 64) ^ fsw));
      __builtin_amdgcn_s_setprio(1);
#pragma unroll
      for (int dt = 0; dt < 4; ++dt) {
        char* vr = (char*)&Vs[cur][dt * 16 + ml][0];
        bf16x8 vf0 = *(const bf16x8*)(vr + (((quad << 4) +  0) ^ fsw));
        bf16x8 vf1 = *(const bf16x8*)(vr + (((quad << 4) + 64) ^ fsw));
        oaccA[dt] = __builtin_amdgcn_mfma_f32_16x16x32_bf16(vf0, pf0, oaccA[dt], 0, 0, 0);
        oaccA[dt] = __builtin_amdgcn_mfma_f32_16x16x32_bf16(vf1, pf1, oaccA[dt], 0, 0, 0);
      }
      __builtin_amdgcn_s_setprio(0);
    }

    // ---- subtile B: exp, pack P^T -> QP (overwrite), PV-B ----
#pragma unroll
    for (int mt = 0; mt < 4; ++mt) {
      float e0 = exp2f(sB[mt][0] * SCL2E), e1 = exp2f(sB[mt][1] * SCL2E),
            e2 = exp2f(sB[mt][2] * SCL2E), e3 = exp2f(sB[mt][3] * SCL2E);
      lsumB += (e0 + e1) + (e2 + e3);
      ushort4 oB;
      oB.x = f2bfu(e0); oB.y = f2bfu(e1); oB.z = f2bfu(e2); oB.w = f2bfu(e3);
      *(ushort4*)(qp + (((mt << 5) + (quad << 3)) ^ fsw)) = oB;
    }
    {
      bf16x8 pf0 = *(const bf16x8*)(qp + (((quad << 4) +  0) ^ fsw));
      bf16x8 pf1 = *(const bf16x8*)(qp + (((quad << 4) + 64) ^ fsw));
      __builtin_amdgcn_s_setprio(1);
#pragma unroll
      for (int dt = 0; dt < 4; ++dt) {
        char* vr = (char*)&Vs[cur][dt * 16 + ml][0];
        bf16x8 vf0 = *(const bf16x8*)(vr + (((quad << 4) +  0) ^ fsw));
        bf16x8 vf1 = *(const bf16x8*)(vr + (((quad << 4) + 64) ^ fsw));
        oaccB[dt] = __builtin_amdgcn_mfma_f32_16x16x32_bf16(vf0, pf0, oaccB[dt], 0, 0, 0);
        oaccB[dt] = __builtin_amdgcn_mfma_f32_16x16x32_bf16(vf1, pf1, oaccB[dt], 0, 0, 0);
      }
      __builtin_amdgcn_s_setprio(0);
    }

    __syncthreads();   // readers of buf[cur] done; writes of buf[nxt] visible
  }

  // ---- cross-quad l reduction (lanes with same ml share q) ----
  lsumA += __shfl_xor(lsumA, 16);
  lsumA += __shfl_xor(lsumA, 32);
  lsumB += __shfl_xor(lsumB, 16);
  lsumB += __shfl_xor(lsumB, 32);
  const size_t lbase = (((size_t)(ks * 2 + b)) * NHEAD + h) * S_LEN;
  const size_t obaseA = (lbase + qrA) * DKH;
  const size_t obaseB = (lbase + qrB) * DKH;
#pragma unroll
  for (int dt = 0; dt < 4; ++dt) {
    *(f32x4*)&Opart[obaseA + dt * 16 + (quad << 2)] = oaccA[dt];
    *(f32x4*)&Opart[obaseB + dt * 16 + (quad << 2)] = oaccB[dt];
  }
  if (quad == 0) {
    Lpart[lbase + qrA] = lsumA;
    Lpart[lbase + qrB] = lsumB;
  }
}

// ---------------------------------------------------------------------------
// combine split-K attention partials: O = (O0+O1)/(l0+l1), bf16 [B][S][H*DKH]
// ---------------------------------------------------------------------------
__global__ __launch_bounds__(256) void attn_combine_kernel(
    const float* __restrict__ Op,   // [KSPLIT][B][H][S][DKH]
    const float* __restrict__ Lp,   // [KSPLIT][B][H][S]
    unsigned short* __restrict__ O) // [B][S][DMODEL]
{
  const int s = blockIdx.x & (S_LEN - 1);
  const int b = blockIdx.x >> 11;
  const int tid = threadIdx.x;
  const size_t ohalf = (size_t)2 * NHEAD * S_LEN * DKH;
  const size_t lhalf = (size_t)2 * NHEAD * S_LEN;
#pragma unroll
  for (int c = tid; c < DMODEL; c += 256) {
    const int hh = c >> 6, dd = c & 63;
    const size_t li = ((size_t)b * NHEAD + hh) * S_LEN + s;
    const size_t oi = li * DKH + dd;
    const float o = Op[oi] + Op[ohalf + oi];
    const float l = Lp[li] + Lp[lhalf + li];
    O[((size_t)b * S_LEN + s) * DMODEL + c] = f2bfu(o / l);
  }
}

// ---------------------------------------------------------------------------
// out = LayerNorm(X + Y [+ Y2]) * w + b; dtype flags (1 = bf16); Y2 nullable
// ---------------------------------------------------------------------------
__global__ __launch_bounds__(256) void add_ln_kernel(
    const void* __restrict__ X, const void* __restrict__ Y,
    const void* __restrict__ Y2,
    const float* __restrict__ w, const float* __restrict__ bvec,
    void* __restrict__ out, int xbf, int ybf, int obf)
{
  __shared__ float buf[DMODEL];
  __shared__ float rbuf[8];
  const int tid  = threadIdx.x;
  const int lane = tid & 63, wv = tid >> 6;
  const size_t base = (size_t)blockIdx.x * DMODEL;

  float s = 0.f, s2 = 0.f;
#pragma unroll
  for (int j = tid; j < DMODEL; j += 256) {
    float xv = xbf ? bfu2f(((const unsigned short*)X)[base + j])
                   : ((const float*)X)[base + j];
    float yv = ybf ? bfu2f(((const unsigned short*)Y)[base + j])
                   : ((const float*)Y)[base + j];
    float v = xv + yv;
    if (Y2) v += ybf ? bfu2f(((const unsigned short*)Y2)[base + j])
                     : ((const float*)Y2)[base + j];
    buf[j] = v; s += v; s2 += v * v;
  }
#pragma unroll
  for (int o = 32; o; o >>= 1) { s += __shfl_xor(s, o); s2 += __shfl_xor(s2, o); }
  if (lane == 0) { rbuf[wv] = s; rbuf[4 + wv] = s2; }
  __syncthreads();
  const float S  = rbuf[0] + rbuf[1] + rbuf[2] + rbuf[3];
  const float S2 = rbuf[4] + rbuf[5] + rbuf[6] + rbuf[7];
  const float mean = S * (1.f / (float)DMODEL);
  const float var  = S2 * (1.f / (float)DMODEL) - mean * mean;
  const float rstd = rsqrtf(var + 1e-5f);
#pragma unroll
  for (int j = tid; j < DMODEL; j += 256) {
    float v = (buf[j] - mean) * rstd * w[j] + bvec[j];
    if (obf) ((unsigned short*)out)[base + j] = f2bfu(v);
    else     ((float*)out)[base + j] = v;
  }
}

// ---------------------------------------------------------------------------
extern "C" void kernel_launch(void* const* d_in, const int* in_sizes, int n_in,
                              void* d_out, int out_size, void* d_ws, size_t ws_size,
                              hipStream_t stream) {
  const float* src  = (const float*)d_in[0];
  const float* Wq   = (const float*)d_in[1];
  const float* bq   = (const float*)d_in[2];
  const float* Wk   = (const float*)d_in[3];
  const float* bk   = (const float*)d_in[4];
  const float* Wv   = (const float*)d_in[5];
  const float* bv   = (const float*)d_in[6];
  const float* Wo   = (const float*)d_in[7];
  const float* bo   = (const float*)d_in[8];
  const float* ln1w = (const float*)d_in[9];
  const float* ln1b = (const float*)d_in[10];
  const float* W1   = (const float*)d_in[11];
  const float* b1   = (const float*)d_in[12];
  const float* W2   = (const float*)d_in[13];
  const float* b2   = (const float*)d_in[14];
  const float* ln2w = (const float*)d_in[15];
  const float* ln2b = (const float*)d_in[16];
  (void)ws_size; (void)in_sizes; (void)n_in; (void)out_size;

  unsigned short* p = (unsigned short*)d_ws;
  const size_t SEG = (size_t)MROWS * DMODEL;
  unsigned short* srcb = p; p += SEG;
  unsigned short* qb   = p; p += SEG;   // Q; later split-K partial z0
  unsigned short* kb_  = p; p += SEG;   // K; later x1
  unsigned short* vbT  = p; p += SEG;   // V^T; later split-K partial z1
  unsigned short* ctx  = p; p += SEG;
  unsigned short* ff   = p; p += (size_t)MROWS * DFF_K;
  unsigned short* wqt  = p; p += (size_t)DMODEL * DMODEL;
  unsigned short* wkt  = p; p += (size_t)DMODEL * DMODEL;
  unsigned short* wvt  = p; p += (size_t)DMODEL * DMODEL;
  unsigned short* wot  = p; p += (size_t)DMODEL * DMODEL;
  unsigned short* w1t  = p; p += (size_t)DMODEL * DFF_K;
  unsigned short* w2t  = p; p += (size_t)DMODEL * DFF_K;
  unsigned short* x1 = kb_;
  // attention split-K scratch (regions dead during attention):
  //   ff  (25.17 MB) exactly fits [KSPLIT][B][H][S][DKH] f32 O-partials
  //   wqt (1.18 MB)  holds [KSPLIT][B][H][S] f32 l-partials (393 KB)
  float* opart = (float*)ff;
  float* lpart = (float*)wqt;

  dim3 blk(256);

  // 0: conversions
  convert_kernel<<<dim3(SEG / 1024), blk, 0, stream>>>(src, srcb, (int)(SEG / 4));
  transpose_conv4_kernel<<<dim3(12, 12, 4), blk, 0, stream>>>(
      Wq, Wk, Wv, Wo, wqt, wkt, wvt, wot);
  transpose_conv_kernel<<<dim3(12, 48), blk, 0, stream>>>(W1, w1t, DMODEL, DFF_K, 0);
  transpose_conv_kernel<<<dim3(48, 12), blk, 0, stream>>>(W2, w2t, DFF_K, DMODEL, 0);

  // 1: fused QKV projections (BN=64, 1152 blocks; V written transposed)
  dim3 gqkv(MROWS / 128, DMODEL / 64, 3);      // 32 x 12 x 3
  qkv_gemm_kernel<<<gqkv, blk, 0, stream>>>(srcb, wqt, wkt, wvt, bq, bk, bv,
                                            qb, kb_, vbT);

  // 2: MFMA flash attention v6b (40KB LDS, 4 blocks/CU) -> f32 partials
  dim3 ga(NHEAD, 2, (S_LEN / 128) * KSPLIT);   // 12 x 2 x 32 = 768 blocks
  flash_attn_mfma<<<ga, blk, 0, stream>>>(qb, kb_, vbT, opart, lpart);
  attn_combine_kernel<<<dim3(MROWS), blk, 0, stream>>>(opart, lpart, ctx);

  // 3: attn_out partials = ctx @ Wo + bo, BN=64 split-K=2 -> qb (z0), vbT (z1)
  dim3 gWo(MROWS / 128, DMODEL / 64, 2);       // 32 x 12 x 2 = 768
  mfma_gemm_kernel<64><<<gWo, blk, 0, stream>>>(ctx, wot, bo, qb,
                                                DMODEL, DMODEL, 0, DMODEL / 2, 2 * SEG);

  // 4: x1 = LN(srcb + p0 + p1)
  add_ln_kernel<<<dim3(MROWS), blk, 0, stream>>>(srcb, qb, vbT,
                                                 ln1w, ln1b, x1, 1, 1, 1);

  // 5: ff = relu(x1 @ W1 + b1)  (BN=128, 768 blocks)
  dim3 gF1(MROWS / 128, DFF_K / 128, 1);       // 32 x 24
  mfma_gemm_kernel<128><<<gF1, blk, 0, stream>>>(x1, w1t, b1, ff,
                                                 DMODEL, DFF_K, 1, DMODEL, 0);

  // 6: y2 partials = ff @ W2 + b2, BN=64 split-K=2 -> qb (z0), vbT (z1)
  dim3 gW2(MROWS / 128, DMODEL / 64, 2);       // 32 x 12 x 2 = 768
  mfma_gemm_kernel<64><<<gW2, blk, 0, stream>>>(ff, w2t, b2, qb,
                                                DFF_K, DMODEL, 0, DFF_K / 2, 2 * SEG);

  // 7: out = LN(x1 + p0 + p1)
  add_ln_kernel<<<dim3(MROWS), blk, 0, stream>>>(x1, qb, vbT,
                                                 ln2w, ln2b, (float*)d_out, 1, 1, 0);
}

// Round 12
// 280.925 us; speedup vs baseline: 1.3684x; 1.0239x over previous
//
#include <hip/hip_runtime.h>
#include <hip/hip_bf16.h>

#define S_LEN 2048
#define DMODEL 768
#define NHEAD 12
#define DKH 64
#define DFF_K 3072
#define MROWS 4096   // B*S
#define KSPLIT 2
#define KHALF (S_LEN / KSPLIT)

typedef __attribute__((ext_vector_type(8))) short bf16x8;
typedef __attribute__((ext_vector_type(8))) unsigned short us8;
typedef __attribute__((ext_vector_type(4))) float f32x4;

__device__ __forceinline__ float bfu2f(unsigned short u) {
  return __uint_as_float(((unsigned int)u) << 16);
}
__device__ __forceinline__ unsigned short f2bfu(float f) {
  __hip_bfloat16 h = __float2bfloat16(f);
  return *reinterpret_cast<unsigned short*>(&h);
}

// async global->LDS 16B: LDS dest is wave-uniform base + lane*16 (HW rule)
__device__ __forceinline__ void async16(const unsigned short* g, unsigned short* l) {
  __builtin_amdgcn_global_load_lds(
      (const __attribute__((address_space(1))) unsigned int*)g,
      (__attribute__((address_space(3))) unsigned int*)l, 16, 0, 0);
}

// ---------------------------------------------------------------------------
// fp32 -> bf16 elementwise convert
// ---------------------------------------------------------------------------
__global__ __launch_bounds__(256) void convert_kernel(
    const float* __restrict__ in, unsigned short* __restrict__ out, int n4)
{
  const int i = blockIdx.x * 256 + threadIdx.x;
  if (i < n4) {
    float4 v = *(const float4*)(in + (size_t)i * 4);
    ushort4 o;
    o.x = f2bfu(v.x); o.y = f2bfu(v.y); o.z = f2bfu(v.z); o.w = f2bfu(v.w);
    *(ushort4*)(out + (size_t)i * 4) = o;
  }
}

// ---------------------------------------------------------------------------
// fp32 [R][C] -> bf16 [C][R] transpose-convert (generic, head or flat).
// ---------------------------------------------------------------------------
__device__ __forceinline__ void transpose_conv_body(
    const float* in, unsigned short* out, int R, int Ctot, int head,
    int bx, int by, int tid)
{
  __shared__ float t[64][68];
  const int r0 = bx * 64;
  const int c0 = by * 64;
  const float* ib;
  int ld;
  if (head) { ib = in + (size_t)by * R * 64; ld = 64; }
  else      { ib = in + c0;                  ld = Ctot; }
  const int lr = tid >> 4;
  const int lc = (tid & 15) << 2;

#pragma unroll
  for (int rr = 0; rr < 4; ++rr) {
    const int row = rr * 16 + lr;
    float4 v = *(const float4*)(ib + (size_t)(r0 + row) * ld + lc);
    t[row][lc + 0] = v.x; t[row][lc + 1] = v.y;
    t[row][lc + 2] = v.z; t[row][lc + 3] = v.w;
  }
  __syncthreads();
#pragma unroll
  for (int rr = 0; rr < 4; ++rr) {
    const int oc = rr * 16 + lr;
    ushort4 o;
    o.x = f2bfu(t[lc + 0][oc]); o.y = f2bfu(t[lc + 1][oc]);
    o.z = f2bfu(t[lc + 2][oc]); o.w = f2bfu(t[lc + 3][oc]);
    *(ushort4*)(out + (size_t)(c0 + oc) * R + r0 + lc) = o;
  }
}

__global__ __launch_bounds__(256) void transpose_conv_kernel(
    const float* __restrict__ in, unsigned short* __restrict__ out,
    int R, int Ctot, int head)
{
  transpose_conv_body(in, out, R, Ctot, head, blockIdx.x, blockIdx.y, threadIdx.x);
}

// fused Wq/Wk/Wv/Wo transpose: z selects tensor; z<3 head-mode
__global__ __launch_bounds__(256) void transpose_conv4_kernel(
    const float* __restrict__ i0, const float* __restrict__ i1,
    const float* __restrict__ i2, const float* __restrict__ i3,
    unsigned short* __restrict__ o0, unsigned short* __restrict__ o1,
    unsigned short* __restrict__ o2, unsigned short* __restrict__ o3)
{
  const int z = blockIdx.z;
  const float* in = (z == 0) ? i0 : (z == 1) ? i1 : (z == 2) ? i2 : i3;
  unsigned short* out = (z == 0) ? o0 : (z == 1) ? o1 : (z == 2) ? o2 : o3;
  transpose_conv_body(in, out, DMODEL, DMODEL, (z < 3) ? 1 : 0,
                      blockIdx.x, blockIdx.y, threadIdx.x);
}

// ---------------------------------------------------------------------------
// Stage one BK=64 tile pair (A: 128 rows, B: BN rows, 64 cols bf16) into
// linear LDS via global_load_lds width-16. Global source is inverse-XOR-
// swizzled (slot ^= row&7) so that swizzled ds_reads see linear data.
// Per-thread instruction count: 4 + BN/32 (6 for BN=64, 8 for BN=128).
// ---------------------------------------------------------------------------
template<int BN>
__device__ __forceinline__ void stage_tile(
    const unsigned short* __restrict__ Ab,   // A + row0*K (+0), element ptr
    const unsigned short* __restrict__ Bb,   // BT + col0*K
    unsigned short* As, unsigned short* Bs,  // LDS linear [rows][64]
    int wid, int lane, int K, int kofs)      // kofs in elements
{
  const int r = lane >> 3;
  const int s = lane & 7;
#pragma unroll
  for (int p = 0; p < 4; ++p) {
    const int row = wid * 32 + p * 8 + r;
    async16(Ab + (size_t)row * K + kofs + ((s ^ (row & 7)) << 3),
            As + (size_t)(wid * 32 + p * 8) * 64);
  }
#pragma unroll
  for (int p = 0; p < BN / 32; ++p) {
    const int row = wid * (BN / 4) + p * 8 + r;
    async16(Bb + (size_t)row * K + kofs + ((s ^ (row & 7)) << 3),
            Bs + (size_t)(wid * (BN / 4) + p * 8) * 64);
  }
}

// ---------------------------------------------------------------------------
// MFMA bf16 GEMM, BK=64, double-buffered LDS filled by global_load_lds,
// XOR-swizzled reads, COUNTED-vmcnt pipeline: next tile's stage loads stay
// in flight across both barriers (proven round-5 structure).
// C = act(A[M x K] @ BT[N x K]^T + bias). BM=128, BN template (64 or 128).
// Grid: x = M row-block, y = N col-block, z = K-split
// (partial z -> C + z*out_stride; bias from z==0 only).
// ---------------------------------------------------------------------------
template<int BN>
__global__ __launch_bounds__(256) void mfma_gemm_kernel(
    const unsigned short* __restrict__ A,
    const unsigned short* __restrict__ BT,
    const float* __restrict__ bias,
    unsigned short* __restrict__ C,
    int K, int N, int relu, int klen, size_t out_stride)
{
  constexpr int WN = (BN == 128) ? 64 : 32;
  constexpr int NJ = WN / 16;
  __shared__ unsigned short As[2][128][64];
  __shared__ unsigned short Bs[2][BN][64];

  const int tid  = threadIdx.x;
  const int wid  = tid >> 6;
  const int lane = tid & 63;
  const int ml   = lane & 15;
  const int quad = lane >> 4;
  const int wm   = (wid & 1) * 64;
  const int wn   = (wid >> 1) * WN;
  const int row0 = blockIdx.x * 128;
  const int col0 = blockIdx.y * BN;
  const int zed  = blockIdx.z;
  const int kb0  = zed * klen;
  const int nsteps = klen >> 6;
  const int fsw = (ml & 7) << 4;   // fragment-read swizzle (row&7 == ml&7)

  const unsigned short* Ab = A  + (size_t)row0 * K + kb0;
  const unsigned short* Bb = BT + (size_t)col0 * K + kb0;

  f32x4 acc[4][NJ];
#pragma unroll
  for (int i = 0; i < 4; ++i)
#pragma unroll
    for (int j = 0; j < NJ; ++j)
#pragma unroll
      for (int r = 0; r < 4; ++r) acc[i][j][r] = 0.f;

  stage_tile<BN>(Ab, Bb, &As[0][0][0], &Bs[0][0][0], wid, lane, K, 0);

  for (int st = 0; st < nsteps; ++st) {
    const int cur = st & 1;
    if (st + 1 < nsteps) {
      stage_tile<BN>(Ab, Bb, &As[cur ^ 1][0][0], &Bs[cur ^ 1][0][0],
                     wid, lane, K, (st + 1) << 6);
      if constexpr (BN == 128) { asm volatile("s_waitcnt vmcnt(8)" ::: "memory"); }
      else                     { asm volatile("s_waitcnt vmcnt(6)" ::: "memory"); }
    } else {
      asm volatile("s_waitcnt vmcnt(0)" ::: "memory");
    }
    __builtin_amdgcn_s_barrier();   // all waves: stage(t) landed in LDS

    const char* Ac = (const char*)&As[cur][0][0];
    const char* Bc = (const char*)&Bs[cur][0][0];
#pragma unroll
    for (int h = 0; h < 2; ++h) {
      bf16x8 af[4], bfr[NJ];
#pragma unroll
      for (int i = 0; i < 4; ++i) {
        const int ar = wm + i * 16 + ml;
        af[i] = *(const bf16x8*)(Ac + ar * 128 + (((h << 6) + (quad << 4)) ^ fsw));
      }
#pragma unroll
      for (int j = 0; j < NJ; ++j) {
        const int br = wn + j * 16 + ml;
        bfr[j] = *(const bf16x8*)(Bc + br * 128 + (((h << 6) + (quad << 4)) ^ fsw));
      }
#pragma unroll
      for (int i = 0; i < 4; ++i)
#pragma unroll
        for (int j = 0; j < NJ; ++j)
          acc[i][j] = __builtin_amdgcn_mfma_f32_16x16x32_bf16(
              af[i], bfr[j], acc[i][j], 0, 0, 0);
    }
    __builtin_amdgcn_s_barrier();   // readers of buf[cur] done
  }

  unsigned short* Cz = C + (size_t)zed * out_stride;
#pragma unroll
  for (int j = 0; j < NJ; ++j) {
    const int col = col0 + wn + j * 16 + ml;
    const float bb = (zed == 0) ? bias[col] : 0.f;
#pragma unroll
    for (int i = 0; i < 4; ++i) {
      const int r0g = row0 + wm + i * 16 + (quad << 2);
#pragma unroll
      for (int r = 0; r < 4; ++r) {
        float v = acc[i][j][r] + bb;
        if (relu) v = fmaxf(v, 0.f);
        Cz[(size_t)(r0g + r) * N + col] = f2bfu(v);
      }
    }
  }
}

// fused QKV projection (per-z, 1152 blocks): z=0 -> Q, z=1 -> K, z=2 -> V
// (VT store). BN=64, BK=64 gload_lds staging + counted vmcnt.
__global__ __launch_bounds__(256) void qkv_gemm_kernel(
    const unsigned short* __restrict__ A,
    const unsigned short* __restrict__ W0, const unsigned short* __restrict__ W1,
    const unsigned short* __restrict__ W2,
    const float* __restrict__ bq, const float* __restrict__ bk,
    const float* __restrict__ bv,
    unsigned short* __restrict__ C0, unsigned short* __restrict__ C1,
    unsigned short* __restrict__ C2)
{
  __shared__ unsigned short As[2][128][64];
  __shared__ unsigned short Bs[2][64][64];
  const int z = blockIdx.z;
  const unsigned short* BT = (z == 0) ? W0 : (z == 1) ? W1 : W2;
  const float* bias = (z == 0) ? bq : (z == 1) ? bk : bv;
  unsigned short* C = (z == 0) ? C0 : (z == 1) ? C1 : C2;
  const int K = DMODEL, N = DMODEL;

  const int tid  = threadIdx.x;
  const int wid  = tid >> 6;
  const int lane = tid & 63;
  const int ml   = lane & 15;
  const int quad = lane >> 4;
  const int wm   = (wid & 1) * 64;
  const int wn   = (wid >> 1) * 32;
  const int row0 = blockIdx.x * 128;
  const int col0 = blockIdx.y * 64;
  const int fsw = (ml & 7) << 4;

  const unsigned short* Ab = A  + (size_t)row0 * K;
  const unsigned short* Bb = BT + (size_t)col0 * K;

  f32x4 acc[4][2];
#pragma unroll
  for (int i = 0; i < 4; ++i)
#pragma unroll
    for (int j = 0; j < 2; ++j)
#pragma unroll
      for (int r = 0; r < 4; ++r) acc[i][j][r] = 0.f;

  stage_tile<64>(Ab, Bb, &As[0][0][0], &Bs[0][0][0], wid, lane, K, 0);

  const int nsteps = K >> 6;   // 12
  for (int st = 0; st < nsteps; ++st) {
    const int cur = st & 1;
    if (st + 1 < nsteps) {
      stage_tile<64>(Ab, Bb, &As[cur ^ 1][0][0], &Bs[cur ^ 1][0][0],
                     wid, lane, K, (st + 1) << 6);
      asm volatile("s_waitcnt vmcnt(6)" ::: "memory");
    } else {
      asm volatile("s_waitcnt vmcnt(0)" ::: "memory");
    }
    __builtin_amdgcn_s_barrier();

    const char* Ac = (const char*)&As[cur][0][0];
    const char* Bc = (const char*)&Bs[cur][0][0];
#pragma unroll
    for (int h = 0; h < 2; ++h) {
      bf16x8 af[4], bfr[2];
#pragma unroll
      for (int i = 0; i < 4; ++i) {
        const int ar = wm + i * 16 + ml;
        af[i] = *(const bf16x8*)(Ac + ar * 128 + (((h << 6) + (quad << 4)) ^ fsw));
      }
#pragma unroll
      for (int j = 0; j < 2; ++j) {
        const int br = wn + j * 16 + ml;
        bfr[j] = *(const bf16x8*)(Bc + br * 128 + (((h << 6) + (quad << 4)) ^ fsw));
      }
#pragma unroll
      for (int i = 0; i < 4; ++i)
#pragma unroll
        for (int j = 0; j < 2; ++j)
          acc[i][j] = __builtin_amdgcn_mfma_f32_16x16x32_bf16(
              af[i], bfr[j], acc[i][j], 0, 0, 0);
    }
    __builtin_amdgcn_s_barrier();
  }

#pragma unroll
  for (int j = 0; j < 2; ++j) {
    const int col = col0 + wn + j * 16 + ml;
    const float bb = bias[col];
#pragma unroll
    for (int i = 0; i < 4; ++i) {
      const int r0g = row0 + wm + i * 16 + (quad << 2);
      if (z == 2) {
        const int bb_ = r0g >> 11, s = r0g & 2047;
        const int hh = col >> 6, dd = col & 63;
        ushort4 o;
        o.x = f2bfu(acc[i][j][0] + bb); o.y = f2bfu(acc[i][j][1] + bb);
        o.z = f2bfu(acc[i][j][2] + bb); o.w = f2bfu(acc[i][j][3] + bb);
        *(ushort4*)(C + ((size_t)((bb_ * NHEAD + hh) * DKH + dd)) * S_LEN + s) = o;
      } else {
#pragma unroll
        for (int r = 0; r < 4; ++r)
          C[(size_t)(r0g + r) * N + col] = f2bfu(acc[i][j][r] + bb);
      }
    }
  }
}

// ---------------------------------------------------------------------------
// MFMA flash attention v4 (REVERTED to round-7 proven 53.3us; v5 32x32
// in-reg-P 55.6, v6 spill 150, v6b A-then-B 56.5 all worse): 2 q-subtiles
// per wave, K/V LDS double-buffer, ONE barrier per tile, XOR swizzle,
// setprio around MFMA clusters, 48KB LDS, launch_bounds(256,3).
// Grid: x = head, y = batch, z = qtile128*KSPLIT + split.
// ---------------------------------------------------------------------------
#define SCL2E 0.1803368822f   // 0.125 * log2(e)
__global__ __launch_bounds__(256, 3) void flash_attn_mfma(
    const unsigned short* __restrict__ Q,
    const unsigned short* __restrict__ K,
    const unsigned short* __restrict__ VT,
    float* __restrict__ Opart,      // [KSPLIT][B][H][S][DKH] f32, unnormalized
    float* __restrict__ Lpart)      // [KSPLIT][B][H][S] f32
{
  __shared__ unsigned short Ks[2][64][64];
  __shared__ unsigned short Vs[2][64][64];     // VT tile: [d][t_local]
  __shared__ unsigned short QP[4][2][16][64];  // per-wave, per-subtile P^T

  const int tid  = threadIdx.x;
  const int wid  = tid >> 6;
  const int lane = tid & 63;
  const int ml   = lane & 15;
  const int quad = lane >> 4;
  const int h    = blockIdx.x, b = blockIdx.y;
  const int q0   = (blockIdx.z >> 1) * 128;
  const int ks   = blockIdx.z & 1;
  const int kt0  = ks * KHALF;

  const size_t qkbase = ((size_t)b * S_LEN) * DMODEL + (size_t)h * DKH;
  const size_t vtbase = ((size_t)(b * NHEAD + h)) * DKH * S_LEN;

  const int sr  = tid >> 2;          // 0..63 staging row
  const int scb = (tid & 3) << 5;    // staging byte col: 0,32,64,96
  const int ssw = (sr & 7) << 4;     // staging swizzle
  const int fsw = (ml & 7) << 4;     // fragment-row swizzle (row&7 == ml&7)

  // ---- Q fragments direct from global (once per block) ----
  const int qrA = q0 + wid * 32 + ml;
  const int qrB = qrA + 16;
  const unsigned short* qpg = Q + qkbase;
  bf16x8 qfA0 = *(const bf16x8*)(qpg + (size_t)qrA * DMODEL + (quad << 3));
  bf16x8 qfA1 = *(const bf16x8*)(qpg + (size_t)qrA * DMODEL + 32 + (quad << 3));
  bf16x8 qfB0 = *(const bf16x8*)(qpg + (size_t)qrB * DMODEL + (quad << 3));
  bf16x8 qfB1 = *(const bf16x8*)(qpg + (size_t)qrB * DMODEL + 32 + (quad << 3));

  const unsigned short* pK = K + qkbase + (size_t)(kt0 + sr) * DMODEL + (scb >> 1);
  const unsigned short* pV = VT + vtbase + (size_t)sr * S_LEN + kt0 + (scb >> 1);

  float lsumA = 0.f, lsumB = 0.f;
  f32x4 oaccA[4], oaccB[4];
#pragma unroll
  for (int dt = 0; dt < 4; ++dt)
#pragma unroll
    for (int r = 0; r < 4; ++r) { oaccA[dt][r] = 0.f; oaccB[dt][r] = 0.f; }

  char* qpA = (char*)&QP[wid][0][ml][0];
  char* qpB = (char*)&QP[wid][1][ml][0];

  // ---- prologue: tile0 -> regs -> buf0; tile1 -> regs; barrier ----
  us8 rk0 = *(const us8*)(pK);
  us8 rk1 = *(const us8*)(pK + 8);
  us8 rv0 = *(const us8*)(pV);
  us8 rv1 = *(const us8*)(pV + 8);
  {
    char* kw = (char*)&Ks[0][sr][0];
    char* vw = (char*)&Vs[0][sr][0];
    *(us8*)(kw + ((scb +  0) ^ ssw)) = rk0;
    *(us8*)(kw + ((scb + 16) ^ ssw)) = rk1;
    *(us8*)(vw + ((scb +  0) ^ ssw)) = rv0;
    *(us8*)(vw + ((scb + 16) ^ ssw)) = rv1;
  }
  rk0 = *(const us8*)(pK + (size_t)64 * DMODEL);
  rk1 = *(const us8*)(pK + (size_t)64 * DMODEL + 8);
  rv0 = *(const us8*)(pV + 64);
  rv1 = *(const us8*)(pV + 64 + 8);
  __syncthreads();

  const int NT = KHALF / 64;   // 16
  for (int t = 0; t < NT; ++t) {
    const int cur = t & 1;
    if (t + 1 < NT) {
      // write tile t+1 (in regs) into buf[cur^1]; overlaps with compute below
      char* kw = (char*)&Ks[cur ^ 1][sr][0];
      char* vw = (char*)&Vs[cur ^ 1][sr][0];
      *(us8*)(kw + ((scb +  0) ^ ssw)) = rk0;
      *(us8*)(kw + ((scb + 16) ^ ssw)) = rk1;
      *(us8*)(vw + ((scb +  0) ^ ssw)) = rv0;
      *(us8*)(vw + ((scb + 16) ^ ssw)) = rv1;
      if (t + 2 < NT) {              // prefetch tile t+2 into regs
        const size_t ko = (size_t)(t + 2) * 64;
        rk0 = *(const us8*)(pK + ko * DMODEL);
        rk1 = *(const us8*)(pK + ko * DMODEL + 8);
        rv0 = *(const us8*)(pV + ko);
        rv1 = *(const us8*)(pV + ko + 8);
      }
    }

    // ---- S^T tile for both q-subtiles: each kf read feeds 2 MFMAs ----
    f32x4 sA[4], sB[4];
#pragma unroll
    for (int mt = 0; mt < 4; ++mt)
#pragma unroll
      for (int r = 0; r < 4; ++r) { sA[mt][r] = 0.f; sB[mt][r] = 0.f; }
    __builtin_amdgcn_s_setprio(1);
#pragma unroll
    for (int mt = 0; mt < 4; ++mt) {
      char* kr = (char*)&Ks[cur][mt * 16 + ml][0];
      bf16x8 kf0 = *(const bf16x8*)(kr + (((quad << 4) +  0) ^ fsw));
      bf16x8 kf1 = *(const bf16x8*)(kr + (((quad << 4) + 64) ^ fsw));
      sA[mt] = __builtin_amdgcn_mfma_f32_16x16x32_bf16(kf0, qfA0, sA[mt], 0, 0, 0);
      sA[mt] = __builtin_amdgcn_mfma_f32_16x16x32_bf16(kf1, qfA1, sA[mt], 0, 0, 0);
      sB[mt] = __builtin_amdgcn_mfma_f32_16x16x32_bf16(kf0, qfB0, sB[mt], 0, 0, 0);
      sB[mt] = __builtin_amdgcn_mfma_f32_16x16x32_bf16(kf1, qfB1, sB[mt], 0, 0, 0);
    }
    __builtin_amdgcn_s_setprio(0);

    // ---- p = exp2(s*scale); pack P^T to per-wave LDS (swizzled) ----
#pragma unroll
    for (int mt = 0; mt < 4; ++mt) {
      float e0 = exp2f(sA[mt][0] * SCL2E), e1 = exp2f(sA[mt][1] * SCL2E),
            e2 = exp2f(sA[mt][2] * SCL2E), e3 = exp2f(sA[mt][3] * SCL2E);
      lsumA += (e0 + e1) + (e2 + e3);
      ushort4 oA;
      oA.x = f2bfu(e0); oA.y = f2bfu(e1); oA.z = f2bfu(e2); oA.w = f2bfu(e3);
      *(ushort4*)(qpA + (((mt << 5) + (quad << 3)) ^ fsw)) = oA;
      e0 = exp2f(sB[mt][0] * SCL2E); e1 = exp2f(sB[mt][1] * SCL2E);
      e2 = exp2f(sB[mt][2] * SCL2E); e3 = exp2f(sB[mt][3] * SCL2E);
      lsumB += (e0 + e1) + (e2 + e3);
      ushort4 oB;
      oB.x = f2bfu(e0); oB.y = f2bfu(e1); oB.z = f2bfu(e2); oB.w = f2bfu(e3);
      *(ushort4*)(qpB + (((mt << 5) + (quad << 3)) ^ fsw)) = oB;
    }
    bf16x8 pfA0 = *(const bf16x8*)(qpA + (((quad << 4) +  0) ^ fsw));
    bf16x8 pfA1 = *(const bf16x8*)(qpA + (((quad << 4) + 64) ^ fsw));
    bf16x8 pfB0 = *(const bf16x8*)(qpB + (((quad << 4) +  0) ^ fsw));
    bf16x8 pfB1 = *(const bf16x8*)(qpB + (((quad << 4) + 64) ^ fsw));

    // ---- PV: each vf read feeds 2 MFMAs ----
    __builtin_amdgcn_s_setprio(1);
#pragma unroll
    for (int dt = 0; dt < 4; ++dt) {
      char* vr = (char*)&Vs[cur][dt * 16 + ml][0];
      bf16x8 vf0 = *(const bf16x8*)(vr + (((quad << 4) +  0) ^ fsw));
      bf16x8 vf1 = *(const bf16x8*)(vr + (((quad << 4) + 64) ^ fsw));
      oaccA[dt] = __builtin_amdgcn_mfma_f32_16x16x32_bf16(vf0, pfA0, oaccA[dt], 0, 0, 0);
      oaccA[dt] = __builtin_amdgcn_mfma_f32_16x16x32_bf16(vf1, pfA1, oaccA[dt], 0, 0, 0);
      oaccB[dt] = __builtin_amdgcn_mfma_f32_16x16x32_bf16(vf0, pfB0, oaccB[dt], 0, 0, 0);
      oaccB[dt] = __builtin_amdgcn_mfma_f32_16x16x32_bf16(vf1, pfB1, oaccB[dt], 0, 0, 0);
    }
    __builtin_amdgcn_s_setprio(0);

    __syncthreads();   // readers of buf[cur] done; writes of buf[nxt] visible
  }

  // ---- cross-quad l reduction (lanes with same ml share q) ----
  lsumA += __shfl_xor(lsumA, 16);
  lsumA += __shfl_xor(lsumA, 32);
  lsumB += __shfl_xor(lsumB, 16);
  lsumB += __shfl_xor(lsumB, 32);
  const size_t lbase = (((size_t)(ks * 2 + b)) * NHEAD + h) * S_LEN;
  const size_t obaseA = (lbase + qrA) * DKH;
  const size_t obaseB = (lbase + qrB) * DKH;
#pragma unroll
  for (int dt = 0; dt < 4; ++dt) {
    *(f32x4*)&Opart[obaseA + dt * 16 + (quad << 2)] = oaccA[dt];
    *(f32x4*)&Opart[obaseB + dt * 16 + (quad << 2)] = oaccB[dt];
  }
  if (quad == 0) {
    Lpart[lbase + qrA] = lsumA;
    Lpart[lbase + qrB] = lsumB;
  }
}

// ---------------------------------------------------------------------------
// combine split-K attention partials: O = (O0+O1)/(l0+l1), bf16 [B][S][H*DKH]
// VECTORIZED: float4 partial reads + ushort4 store (was scalar; G13).
// 192 active lanes x 4 cols = 768.
// ---------------------------------------------------------------------------
__global__ __launch_bounds__(256) void attn_combine_kernel(
    const float* __restrict__ Op,   // [KSPLIT][B][H][S][DKH]
    const float* __restrict__ Lp,   // [KSPLIT][B][H][S]
    unsigned short* __restrict__ O) // [B][S][DMODEL]
{
  const int s = blockIdx.x & (S_LEN - 1);
  const int b = blockIdx.x >> 11;
  const int tid = threadIdx.x;
  if (tid >= DMODEL / 4) return;    // 192 lanes active
  const size_t ohalf = (size_t)2 * NHEAD * S_LEN * DKH;
  const size_t lhalf = (size_t)2 * NHEAD * S_LEN;
  const int c = tid * 4;
  const int hh = c >> 6, dd = c & 63;
  const size_t li = ((size_t)b * NHEAD + hh) * S_LEN + s;
  const size_t oi = li * DKH + dd;
  float4 o0 = *(const float4*)&Op[oi];
  float4 o1 = *(const float4*)&Op[ohalf + oi];
  const float l = Lp[li] + Lp[lhalf + li];
  ushort4 o;
  o.x = f2bfu((o0.x + o1.x) / l);
  o.y = f2bfu((o0.y + o1.y) / l);
  o.z = f2bfu((o0.z + o1.z) / l);
  o.w = f2bfu((o0.w + o1.w) / l);
  *(ushort4*)&O[((size_t)b * S_LEN + s) * DMODEL + c] = o;
}

// ---------------------------------------------------------------------------
// out = LayerNorm(X + Y [+ Y2]) * w + b; dtype flags (1 = bf16); Y2 nullable.
// VECTORIZED (G13): 192 active lanes x ushort4/float4 (was scalar bf16).
// ---------------------------------------------------------------------------
__global__ __launch_bounds__(256) void add_ln_kernel(
    const void* __restrict__ X, const void* __restrict__ Y,
    const void* __restrict__ Y2,
    const float* __restrict__ w, const float* __restrict__ bvec,
    void* __restrict__ out, int xbf, int ybf, int obf)
{
  __shared__ float buf[DMODEL];
  __shared__ float rbuf[8];
  const int tid  = threadIdx.x;
  const int lane = tid & 63, wv = tid >> 6;
  const size_t base = (size_t)blockIdx.x * DMODEL;
  const int j = tid * 4;            // 192 lanes active (j < 768)

  float v[4];
  float s = 0.f, s2 = 0.f;
  if (j < DMODEL) {
    if (xbf) {
      ushort4 xv = *(const ushort4*)((const unsigned short*)X + base + j);
      v[0] = bfu2f(xv.x); v[1] = bfu2f(xv.y); v[2] = bfu2f(xv.z); v[3] = bfu2f(xv.w);
    } else {
      float4 xv = *(const float4*)((const float*)X + base + j);
      v[0] = xv.x; v[1] = xv.y; v[2] = xv.z; v[3] = xv.w;
    }
    if (ybf) {
      ushort4 yv = *(const ushort4*)((const unsigned short*)Y + base + j);
      v[0] += bfu2f(yv.x); v[1] += bfu2f(yv.y); v[2] += bfu2f(yv.z); v[3] += bfu2f(yv.w);
    } else {
      float4 yv = *(const float4*)((const float*)Y + base + j);
      v[0] += yv.x; v[1] += yv.y; v[2] += yv.z; v[3] += yv.w;
    }
    if (Y2) {
      if (ybf) {
        ushort4 yv = *(const ushort4*)((const unsigned short*)Y2 + base + j);
        v[0] += bfu2f(yv.x); v[1] += bfu2f(yv.y); v[2] += bfu2f(yv.z); v[3] += bfu2f(yv.w);
      } else {
        float4 yv = *(const float4*)((const float*)Y2 + base + j);
        v[0] += yv.x; v[1] += yv.y; v[2] += yv.z; v[3] += yv.w;
      }
    }
#pragma unroll
    for (int k = 0; k < 4; ++k) {
      buf[j + k] = v[k];
      s += v[k]; s2 += v[k] * v[k];
    }
  }
#pragma unroll
  for (int o = 32; o; o >>= 1) { s += __shfl_xor(s, o); s2 += __shfl_xor(s2, o); }
  if (lane == 0) { rbuf[wv] = s; rbuf[4 + wv] = s2; }
  __syncthreads();
  const float S  = rbuf[0] + rbuf[1] + rbuf[2] + rbuf[3];
  const float S2 = rbuf[4] + rbuf[5] + rbuf[6] + rbuf[7];
  const float mean = S * (1.f / (float)DMODEL);
  const float var  = S2 * (1.f / (float)DMODEL) - mean * mean;
  const float rstd = rsqrtf(var + 1e-5f);
  if (j < DMODEL) {
    float o[4];
#pragma unroll
    for (int k = 0; k < 4; ++k)
      o[k] = (buf[j + k] - mean) * rstd * w[j + k] + bvec[j + k];
    if (obf) {
      ushort4 ov;
      ov.x = f2bfu(o[0]); ov.y = f2bfu(o[1]); ov.z = f2bfu(o[2]); ov.w = f2bfu(o[3]);
      *(ushort4*)((unsigned short*)out + base + j) = ov;
    } else {
      float4 ov;
      ov.x = o[0]; ov.y = o[1]; ov.z = o[2]; ov.w = o[3];
      *(float4*)((float*)out + base + j) = ov;
    }
  }
}

// ---------------------------------------------------------------------------
extern "C" void kernel_launch(void* const* d_in, const int* in_sizes, int n_in,
                              void* d_out, int out_size, void* d_ws, size_t ws_size,
                              hipStream_t stream) {
  const float* src  = (const float*)d_in[0];
  const float* Wq   = (const float*)d_in[1];
  const float* bq   = (const float*)d_in[2];
  const float* Wk   = (const float*)d_in[3];
  const float* bk   = (const float*)d_in[4];
  const float* Wv   = (const float*)d_in[5];
  const float* bv   = (const float*)d_in[6];
  const float* Wo   = (const float*)d_in[7];
  const float* bo   = (const float*)d_in[8];
  const float* ln1w = (const float*)d_in[9];
  const float* ln1b = (const float*)d_in[10];
  const float* W1   = (const float*)d_in[11];
  const float* b1   = (const float*)d_in[12];
  const float* W2   = (const float*)d_in[13];
  const float* b2   = (const float*)d_in[14];
  const float* ln2w = (const float*)d_in[15];
  const float* ln2b = (const float*)d_in[16];
  (void)ws_size; (void)in_sizes; (void)n_in; (void)out_size;

  unsigned short* p = (unsigned short*)d_ws;
  const size_t SEG = (size_t)MROWS * DMODEL;
  unsigned short* srcb = p; p += SEG;
  unsigned short* qb   = p; p += SEG;   // Q; later split-K partial z0
  unsigned short* kb_  = p; p += SEG;   // K; later x1
  unsigned short* vbT  = p; p += SEG;   // V^T; later split-K partial z1
  unsigned short* ctx  = p; p += SEG;
  unsigned short* ff   = p; p += (size_t)MROWS * DFF_K;
  unsigned short* wqt  = p; p += (size_t)DMODEL * DMODEL;
  unsigned short* wkt  = p; p += (size_t)DMODEL * DMODEL;
  unsigned short* wvt  = p; p += (size_t)DMODEL * DMODEL;
  unsigned short* wot  = p; p += (size_t)DMODEL * DMODEL;
  unsigned short* w1t  = p; p += (size_t)DMODEL * DFF_K;
  unsigned short* w2t  = p; p += (size_t)DMODEL * DFF_K;
  unsigned short* x1 = kb_;
  // attention split-K scratch (regions dead during attention):
  //   ff  (25.17 MB) exactly fits [KSPLIT][B][H][S][DKH] f32 O-partials
  //   wqt (1.18 MB)  holds [KSPLIT][B][H][S] f32 l-partials (393 KB)
  float* opart = (float*)ff;
  float* lpart = (float*)wqt;

  dim3 blk(256);

  // 0: conversions
  convert_kernel<<<dim3(SEG / 1024), blk, 0, stream>>>(src, srcb, (int)(SEG / 4));
  transpose_conv4_kernel<<<dim3(12, 12, 4), blk, 0, stream>>>(
      Wq, Wk, Wv, Wo, wqt, wkt, wvt, wot);
  transpose_conv_kernel<<<dim3(12, 48), blk, 0, stream>>>(W1, w1t, DMODEL, DFF_K, 0);
  transpose_conv_kernel<<<dim3(48, 12), blk, 0, stream>>>(W2, w2t, DFF_K, DMODEL, 0);

  // 1: fused QKV projections (BN=64, 1152 blocks; V written transposed)
  dim3 gqkv(MROWS / 128, DMODEL / 64, 3);      // 32 x 12 x 3
  qkv_gemm_kernel<<<gqkv, blk, 0, stream>>>(srcb, wqt, wkt, wvt, bq, bk, bv,
                                            qb, kb_, vbT);

  // 2: MFMA flash attention v4 (dbuf K/V, 1 barrier/tile) -> f32 partials
  dim3 ga(NHEAD, 2, (S_LEN / 128) * KSPLIT);   // 12 x 2 x 32 = 768 blocks
  flash_attn_mfma<<<ga, blk, 0, stream>>>(qb, kb_, vbT, opart, lpart);
  attn_combine_kernel<<<dim3(MROWS), blk, 0, stream>>>(opart, lpart, ctx);

  // 3: attn_out partials = ctx @ Wo + bo, BN=64 split-K=2 -> qb (z0), vbT (z1)
  dim3 gWo(MROWS / 128, DMODEL / 64, 2);       // 32 x 12 x 2 = 768
  mfma_gemm_kernel<64><<<gWo, blk, 0, stream>>>(ctx, wot, bo, qb,
                                                DMODEL, DMODEL, 0, DMODEL / 2, 2 * SEG);

  // 4: x1 = LN(srcb + p0 + p1)
  add_ln_kernel<<<dim3(MROWS), blk, 0, stream>>>(srcb, qb, vbT,
                                                 ln1w, ln1b, x1, 1, 1, 1);

  // 5: ff = relu(x1 @ W1 + b1)  (BN=128, 768 blocks)
  dim3 gF1(MROWS / 128, DFF_K / 128, 1);       // 32 x 24
  mfma_gemm_kernel<128><<<gF1, blk, 0, stream>>>(x1, w1t, b1, ff,
                                                 DMODEL, DFF_K, 1, DMODEL, 0);

  // 6: y2 partials = ff @ W2 + b2, BN=64 split-K=2 -> qb (z0), vbT (z1)
  dim3 gW2(MROWS / 128, DMODEL / 64, 2);       // 32 x 12 x 2 = 768
  mfma_gemm_kernel<64><<<gW2, blk, 0, stream>>>(ff, w2t, b2, qb,
                                                DFF_K, DMODEL, 0, DFF_K / 2, 2 * SEG);

  // 7: out = LN(x1 + p0 + p1)
  add_ln_kernel<<<dim3(MROWS), blk, 0, stream>>>(x1, qb, vbT,
                                                 ln2w, ln2b, (float*)d_out, 1, 1, 0);
}

// Round 13
// 277.466 us; speedup vs baseline: 1.3854x; 1.0125x over previous
//
#include <hip/hip_runtime.h>
#include <hip/hip_bf16.h>

#define S_LEN 2048
#define DMODEL 768
#define NHEAD 12
#define DKH 64
#define DFF_K 3072
#define MROWS 4096   // B*S
#define KSPLIT 2
#define KHALF (S_LEN / KSPLIT)

typedef __attribute__((ext_vector_type(8))) short bf16x8;
typedef __attribute__((ext_vector_type(8))) unsigned short us8;
typedef __attribute__((ext_vector_type(4))) float f32x4;

__device__ __forceinline__ float bfu2f(unsigned short u) {
  return __uint_as_float(((unsigned int)u) << 16);
}
__device__ __forceinline__ unsigned short f2bfu(float f) {
  __hip_bfloat16 h = __float2bfloat16(f);
  return *reinterpret_cast<unsigned short*>(&h);
}

// async global->LDS 16B: LDS dest is wave-uniform base + lane*16 (HW rule)
__device__ __forceinline__ void async16(const unsigned short* g, unsigned short* l) {
  __builtin_amdgcn_global_load_lds(
      (const __attribute__((address_space(1))) unsigned int*)g,
      (__attribute__((address_space(3))) unsigned int*)l, 16, 0, 0);
}

// ---------------------------------------------------------------------------
// fp32 -> bf16 elementwise convert
// ---------------------------------------------------------------------------
__global__ __launch_bounds__(256) void convert_kernel(
    const float* __restrict__ in, unsigned short* __restrict__ out, int n4)
{
  const int i = blockIdx.x * 256 + threadIdx.x;
  if (i < n4) {
    float4 v = *(const float4*)(in + (size_t)i * 4);
    ushort4 o;
    o.x = f2bfu(v.x); o.y = f2bfu(v.y); o.z = f2bfu(v.z); o.w = f2bfu(v.w);
    *(ushort4*)(out + (size_t)i * 4) = o;
  }
}

// ---------------------------------------------------------------------------
// fp32 [R][C] -> bf16 [C][R] transpose-convert (generic, head or flat).
// ---------------------------------------------------------------------------
__device__ __forceinline__ void transpose_conv_body(
    const float* in, unsigned short* out, int R, int Ctot, int head,
    int bx, int by, int tid)
{
  __shared__ float t[64][68];
  const int r0 = bx * 64;
  const int c0 = by * 64;
  const float* ib;
  int ld;
  if (head) { ib = in + (size_t)by * R * 64; ld = 64; }
  else      { ib = in + c0;                  ld = Ctot; }
  const int lr = tid >> 4;
  const int lc = (tid & 15) << 2;

#pragma unroll
  for (int rr = 0; rr < 4; ++rr) {
    const int row = rr * 16 + lr;
    float4 v = *(const float4*)(ib + (size_t)(r0 + row) * ld + lc);
    t[row][lc + 0] = v.x; t[row][lc + 1] = v.y;
    t[row][lc + 2] = v.z; t[row][lc + 3] = v.w;
  }
  __syncthreads();
#pragma unroll
  for (int rr = 0; rr < 4; ++rr) {
    const int oc = rr * 16 + lr;
    ushort4 o;
    o.x = f2bfu(t[lc + 0][oc]); o.y = f2bfu(t[lc + 1][oc]);
    o.z = f2bfu(t[lc + 2][oc]); o.w = f2bfu(t[lc + 3][oc]);
    *(ushort4*)(out + (size_t)(c0 + oc) * R + r0 + lc) = o;
  }
}

__global__ __launch_bounds__(256) void transpose_conv_kernel(
    const float* __restrict__ in, unsigned short* __restrict__ out,
    int R, int Ctot, int head)
{
  transpose_conv_body(in, out, R, Ctot, head, blockIdx.x, blockIdx.y, threadIdx.x);
}

// fused Wq/Wk/Wv/Wo transpose: z selects tensor; z<3 head-mode
__global__ __launch_bounds__(256) void transpose_conv4_kernel(
    const float* __restrict__ i0, const float* __restrict__ i1,
    const float* __restrict__ i2, const float* __restrict__ i3,
    unsigned short* __restrict__ o0, unsigned short* __restrict__ o1,
    unsigned short* __restrict__ o2, unsigned short* __restrict__ o3)
{
  const int z = blockIdx.z;
  const float* in = (z == 0) ? i0 : (z == 1) ? i1 : (z == 2) ? i2 : i3;
  unsigned short* out = (z == 0) ? o0 : (z == 1) ? o1 : (z == 2) ? o2 : o3;
  transpose_conv_body(in, out, DMODEL, DMODEL, (z < 3) ? 1 : 0,
                      blockIdx.x, blockIdx.y, threadIdx.x);
}

// ---------------------------------------------------------------------------
// Stage one BK=64 tile pair (A: 128 rows, B: BN rows, 64 cols bf16) into
// linear LDS via global_load_lds width-16. Global source is inverse-XOR-
// swizzled (slot ^= row&7) so that swizzled ds_reads see linear data.
// Per-thread instruction count: 4 + BN/32 (6 for BN=64, 8 for BN=128).
// ---------------------------------------------------------------------------
template<int BN>
__device__ __forceinline__ void stage_tile(
    const unsigned short* __restrict__ Ab,   // A + row0*K (+0), element ptr
    const unsigned short* __restrict__ Bb,   // BT + col0*K
    unsigned short* As, unsigned short* Bs,  // LDS linear [rows][64]
    int wid, int lane, int K, int kofs)      // kofs in elements
{
  const int r = lane >> 3;
  const int s = lane & 7;
#pragma unroll
  for (int p = 0; p < 4; ++p) {
    const int row = wid * 32 + p * 8 + r;
    async16(Ab + (size_t)row * K + kofs + ((s ^ (row & 7)) << 3),
            As + (size_t)(wid * 32 + p * 8) * 64);
  }
#pragma unroll
  for (int p = 0; p < BN / 32; ++p) {
    const int row = wid * (BN / 4) + p * 8 + r;
    async16(Bb + (size_t)row * K + kofs + ((s ^ (row & 7)) << 3),
            Bs + (size_t)(wid * (BN / 4) + p * 8) * 64);
  }
}

// ---------------------------------------------------------------------------
// MFMA bf16 GEMM, BK=64, double-buffered LDS filled by global_load_lds,
// XOR-swizzled reads, COUNTED-vmcnt pipeline: next tile's stage loads stay
// in flight across both barriers (proven round-5 structure).
// C = act(A[M x K] @ BT[N x K]^T + bias). BM=128, BN template (64 or 128).
// Grid: x = M row-block, y = N col-block, z = K-split
// (partial z -> C + z*out_stride; bias from z==0 only).
// ---------------------------------------------------------------------------
template<int BN>
__global__ __launch_bounds__(256) void mfma_gemm_kernel(
    const unsigned short* __restrict__ A,
    const unsigned short* __restrict__ BT,
    const float* __restrict__ bias,
    unsigned short* __restrict__ C,
    int K, int N, int relu, int klen, size_t out_stride)
{
  constexpr int WN = (BN == 128) ? 64 : 32;
  constexpr int NJ = WN / 16;
  __shared__ unsigned short As[2][128][64];
  __shared__ unsigned short Bs[2][BN][64];

  const int tid  = threadIdx.x;
  const int wid  = tid >> 6;
  const int lane = tid & 63;
  const int ml   = lane & 15;
  const int quad = lane >> 4;
  const int wm   = (wid & 1) * 64;
  const int wn   = (wid >> 1) * WN;
  const int row0 = blockIdx.x * 128;
  const int col0 = blockIdx.y * BN;
  const int zed  = blockIdx.z;
  const int kb0  = zed * klen;
  const int nsteps = klen >> 6;
  const int fsw = (ml & 7) << 4;   // fragment-read swizzle (row&7 == ml&7)

  const unsigned short* Ab = A  + (size_t)row0 * K + kb0;
  const unsigned short* Bb = BT + (size_t)col0 * K + kb0;

  f32x4 acc[4][NJ];
#pragma unroll
  for (int i = 0; i < 4; ++i)
#pragma unroll
    for (int j = 0; j < NJ; ++j)
#pragma unroll
      for (int r = 0; r < 4; ++r) acc[i][j][r] = 0.f;

  stage_tile<BN>(Ab, Bb, &As[0][0][0], &Bs[0][0][0], wid, lane, K, 0);

  for (int st = 0; st < nsteps; ++st) {
    const int cur = st & 1;
    if (st + 1 < nsteps) {
      stage_tile<BN>(Ab, Bb, &As[cur ^ 1][0][0], &Bs[cur ^ 1][0][0],
                     wid, lane, K, (st + 1) << 6);
      if constexpr (BN == 128) { asm volatile("s_waitcnt vmcnt(8)" ::: "memory"); }
      else                     { asm volatile("s_waitcnt vmcnt(6)" ::: "memory"); }
    } else {
      asm volatile("s_waitcnt vmcnt(0)" ::: "memory");
    }
    __builtin_amdgcn_s_barrier();   // all waves: stage(t) landed in LDS

    const char* Ac = (const char*)&As[cur][0][0];
    const char* Bc = (const char*)&Bs[cur][0][0];
#pragma unroll
    for (int h = 0; h < 2; ++h) {
      bf16x8 af[4], bfr[NJ];
#pragma unroll
      for (int i = 0; i < 4; ++i) {
        const int ar = wm + i * 16 + ml;
        af[i] = *(const bf16x8*)(Ac + ar * 128 + (((h << 6) + (quad << 4)) ^ fsw));
      }
#pragma unroll
      for (int j = 0; j < NJ; ++j) {
        const int br = wn + j * 16 + ml;
        bfr[j] = *(const bf16x8*)(Bc + br * 128 + (((h << 6) + (quad << 4)) ^ fsw));
      }
#pragma unroll
      for (int i = 0; i < 4; ++i)
#pragma unroll
        for (int j = 0; j < NJ; ++j)
          acc[i][j] = __builtin_amdgcn_mfma_f32_16x16x32_bf16(
              af[i], bfr[j], acc[i][j], 0, 0, 0);
    }
    __builtin_amdgcn_s_barrier();   // readers of buf[cur] done
  }

  unsigned short* Cz = C + (size_t)zed * out_stride;
#pragma unroll
  for (int j = 0; j < NJ; ++j) {
    const int col = col0 + wn + j * 16 + ml;
    const float bb = (zed == 0) ? bias[col] : 0.f;
#pragma unroll
    for (int i = 0; i < 4; ++i) {
      const int r0g = row0 + wm + i * 16 + (quad << 2);
#pragma unroll
      for (int r = 0; r < 4; ++r) {
        float v = acc[i][j][r] + bb;
        if (relu) v = fmaxf(v, 0.f);
        Cz[(size_t)(r0g + r) * N + col] = f2bfu(v);
      }
    }
  }
}

// fused QKV projection, BN=128 (was 64: ratio MFMA:ds_read 2.0 vs 1.33;
// m92-m112 ladder shows small tiles lose big at fixed structure).
// 576 blocks (32 x 6 x 3), 64KB LDS -> 2 blocks/CU. z=0 -> Q, z=1 -> K,
// z=2 -> V (VT store). BK=64 gload_lds staging + counted vmcnt.
__global__ __launch_bounds__(256) void qkv_gemm_kernel(
    const unsigned short* __restrict__ A,
    const unsigned short* __restrict__ W0, const unsigned short* __restrict__ W1,
    const unsigned short* __restrict__ W2,
    const float* __restrict__ bq, const float* __restrict__ bk,
    const float* __restrict__ bv,
    unsigned short* __restrict__ C0, unsigned short* __restrict__ C1,
    unsigned short* __restrict__ C2)
{
  __shared__ unsigned short As[2][128][64];
  __shared__ unsigned short Bs[2][128][64];
  const int z = blockIdx.z;
  const unsigned short* BT = (z == 0) ? W0 : (z == 1) ? W1 : W2;
  const float* bias = (z == 0) ? bq : (z == 1) ? bk : bv;
  unsigned short* C = (z == 0) ? C0 : (z == 1) ? C1 : C2;
  const int K = DMODEL, N = DMODEL;

  const int tid  = threadIdx.x;
  const int wid  = tid >> 6;
  const int lane = tid & 63;
  const int ml   = lane & 15;
  const int quad = lane >> 4;
  const int wm   = (wid & 1) * 64;
  const int wn   = (wid >> 1) * 64;
  const int row0 = blockIdx.x * 128;
  const int col0 = blockIdx.y * 128;
  const int fsw = (ml & 7) << 4;

  const unsigned short* Ab = A  + (size_t)row0 * K;
  const unsigned short* Bb = BT + (size_t)col0 * K;

  f32x4 acc[4][4];
#pragma unroll
  for (int i = 0; i < 4; ++i)
#pragma unroll
    for (int j = 0; j < 4; ++j)
#pragma unroll
      for (int r = 0; r < 4; ++r) acc[i][j][r] = 0.f;

  stage_tile<128>(Ab, Bb, &As[0][0][0], &Bs[0][0][0], wid, lane, K, 0);

  const int nsteps = K >> 6;   // 12
  for (int st = 0; st < nsteps; ++st) {
    const int cur = st & 1;
    if (st + 1 < nsteps) {
      stage_tile<128>(Ab, Bb, &As[cur ^ 1][0][0], &Bs[cur ^ 1][0][0],
                      wid, lane, K, (st + 1) << 6);
      asm volatile("s_waitcnt vmcnt(8)" ::: "memory");
    } else {
      asm volatile("s_waitcnt vmcnt(0)" ::: "memory");
    }
    __builtin_amdgcn_s_barrier();

    const char* Ac = (const char*)&As[cur][0][0];
    const char* Bc = (const char*)&Bs[cur][0][0];
#pragma unroll
    for (int h = 0; h < 2; ++h) {
      bf16x8 af[4], bfr[4];
#pragma unroll
      for (int i = 0; i < 4; ++i) {
        const int ar = wm + i * 16 + ml;
        af[i] = *(const bf16x8*)(Ac + ar * 128 + (((h << 6) + (quad << 4)) ^ fsw));
      }
#pragma unroll
      for (int j = 0; j < 4; ++j) {
        const int br = wn + j * 16 + ml;
        bfr[j] = *(const bf16x8*)(Bc + br * 128 + (((h << 6) + (quad << 4)) ^ fsw));
      }
#pragma unroll
      for (int i = 0; i < 4; ++i)
#pragma unroll
        for (int j = 0; j < 4; ++j)
          acc[i][j] = __builtin_amdgcn_mfma_f32_16x16x32_bf16(
              af[i], bfr[j], acc[i][j], 0, 0, 0);
    }
    __builtin_amdgcn_s_barrier();
  }

#pragma unroll
  for (int j = 0; j < 4; ++j) {
    const int col = col0 + wn + j * 16 + ml;
    const float bb = bias[col];
#pragma unroll
    for (int i = 0; i < 4; ++i) {
      const int r0g = row0 + wm + i * 16 + (quad << 2);
      if (z == 2) {
        const int bb_ = r0g >> 11, s = r0g & 2047;
        const int hh = col >> 6, dd = col & 63;
        ushort4 o;
        o.x = f2bfu(acc[i][j][0] + bb); o.y = f2bfu(acc[i][j][1] + bb);
        o.z = f2bfu(acc[i][j][2] + bb); o.w = f2bfu(acc[i][j][3] + bb);
        *(ushort4*)(C + ((size_t)((bb_ * NHEAD + hh) * DKH + dd)) * S_LEN + s) = o;
      } else {
#pragma unroll
        for (int r = 0; r < 4; ++r)
          C[(size_t)(r0g + r) * N + col] = f2bfu(acc[i][j][r] + bb);
      }
    }
  }
}

// ---------------------------------------------------------------------------
// MFMA flash attention v4 (proven 51.6-53.3us floor; v5/v6/v6b all worse):
// 2 q-subtiles per wave, K/V LDS double-buffer, ONE barrier per tile, XOR
// swizzle, setprio around MFMA clusters, 48KB LDS, launch_bounds(256,3).
// Grid: x = head, y = batch, z = qtile128*KSPLIT + split.
// ---------------------------------------------------------------------------
#define SCL2E 0.1803368822f   // 0.125 * log2(e)
__global__ __launch_bounds__(256, 3) void flash_attn_mfma(
    const unsigned short* __restrict__ Q,
    const unsigned short* __restrict__ K,
    const unsigned short* __restrict__ VT,
    float* __restrict__ Opart,      // [KSPLIT][B][H][S][DKH] f32, unnormalized
    float* __restrict__ Lpart)      // [KSPLIT][B][H][S] f32
{
  __shared__ unsigned short Ks[2][64][64];
  __shared__ unsigned short Vs[2][64][64];     // VT tile: [d][t_local]
  __shared__ unsigned short QP[4][2][16][64];  // per-wave, per-subtile P^T

  const int tid  = threadIdx.x;
  const int wid  = tid >> 6;
  const int lane = tid & 63;
  const int ml   = lane & 15;
  const int quad = lane >> 4;
  const int h    = blockIdx.x, b = blockIdx.y;
  const int q0   = (blockIdx.z >> 1) * 128;
  const int ks   = blockIdx.z & 1;
  const int kt0  = ks * KHALF;

  const size_t qkbase = ((size_t)b * S_LEN) * DMODEL + (size_t)h * DKH;
  const size_t vtbase = ((size_t)(b * NHEAD + h)) * DKH * S_LEN;

  const int sr  = tid >> 2;          // 0..63 staging row
  const int scb = (tid & 3) << 5;    // staging byte col: 0,32,64,96
  const int ssw = (sr & 7) << 4;     // staging swizzle
  const int fsw = (ml & 7) << 4;     // fragment-row swizzle (row&7 == ml&7)

  // ---- Q fragments direct from global (once per block) ----
  const int qrA = q0 + wid * 32 + ml;
  const int qrB = qrA + 16;
  const unsigned short* qpg = Q + qkbase;
  bf16x8 qfA0 = *(const bf16x8*)(qpg + (size_t)qrA * DMODEL + (quad << 3));
  bf16x8 qfA1 = *(const bf16x8*)(qpg + (size_t)qrA * DMODEL + 32 + (quad << 3));
  bf16x8 qfB0 = *(const bf16x8*)(qpg + (size_t)qrB * DMODEL + (quad << 3));
  bf16x8 qfB1 = *(const bf16x8*)(qpg + (size_t)qrB * DMODEL + 32 + (quad << 3));

  const unsigned short* pK = K + qkbase + (size_t)(kt0 + sr) * DMODEL + (scb >> 1);
  const unsigned short* pV = VT + vtbase + (size_t)sr * S_LEN + kt0 + (scb >> 1);

  float lsumA = 0.f, lsumB = 0.f;
  f32x4 oaccA[4], oaccB[4];
#pragma unroll
  for (int dt = 0; dt < 4; ++dt)
#pragma unroll
    for (int r = 0; r < 4; ++r) { oaccA[dt][r] = 0.f; oaccB[dt][r] = 0.f; }

  char* qpA = (char*)&QP[wid][0][ml][0];
  char* qpB = (char*)&QP[wid][1][ml][0];

  // ---- prologue: tile0 -> regs -> buf0; tile1 -> regs; barrier ----
  us8 rk0 = *(const us8*)(pK);
  us8 rk1 = *(const us8*)(pK + 8);
  us8 rv0 = *(const us8*)(pV);
  us8 rv1 = *(const us8*)(pV + 8);
  {
    char* kw = (char*)&Ks[0][sr][0];
    char* vw = (char*)&Vs[0][sr][0];
    *(us8*)(kw + ((scb +  0) ^ ssw)) = rk0;
    *(us8*)(kw + ((scb + 16) ^ ssw)) = rk1;
    *(us8*)(vw + ((scb +  0) ^ ssw)) = rv0;
    *(us8*)(vw + ((scb + 16) ^ ssw)) = rv1;
  }
  rk0 = *(const us8*)(pK + (size_t)64 * DMODEL);
  rk1 = *(const us8*)(pK + (size_t)64 * DMODEL + 8);
  rv0 = *(const us8*)(pV + 64);
  rv1 = *(const us8*)(pV + 64 + 8);
  __syncthreads();

  const int NT = KHALF / 64;   // 16
  for (int t = 0; t < NT; ++t) {
    const int cur = t & 1;
    if (t + 1 < NT) {
      // write tile t+1 (in regs) into buf[cur^1]; overlaps with compute below
      char* kw = (char*)&Ks[cur ^ 1][sr][0];
      char* vw = (char*)&Vs[cur ^ 1][sr][0];
      *(us8*)(kw + ((scb +  0) ^ ssw)) = rk0;
      *(us8*)(kw + ((scb + 16) ^ ssw)) = rk1;
      *(us8*)(vw + ((scb +  0) ^ ssw)) = rv0;
      *(us8*)(vw + ((scb + 16) ^ ssw)) = rv1;
      if (t + 2 < NT) {              // prefetch tile t+2 into regs
        const size_t ko = (size_t)(t + 2) * 64;
        rk0 = *(const us8*)(pK + ko * DMODEL);
        rk1 = *(const us8*)(pK + ko * DMODEL + 8);
        rv0 = *(const us8*)(pV + ko);
        rv1 = *(const us8*)(pV + ko + 8);
      }
    }

    // ---- S^T tile for both q-subtiles: each kf read feeds 2 MFMAs ----
    f32x4 sA[4], sB[4];
#pragma unroll
    for (int mt = 0; mt < 4; ++mt)
#pragma unroll
      for (int r = 0; r < 4; ++r) { sA[mt][r] = 0.f; sB[mt][r] = 0.f; }
    __builtin_amdgcn_s_setprio(1);
#pragma unroll
    for (int mt = 0; mt < 4; ++mt) {
      char* kr = (char*)&Ks[cur][mt * 16 + ml][0];
      bf16x8 kf0 = *(const bf16x8*)(kr + (((quad << 4) +  0) ^ fsw));
      bf16x8 kf1 = *(const bf16x8*)(kr + (((quad << 4) + 64) ^ fsw));
      sA[mt] = __builtin_amdgcn_mfma_f32_16x16x32_bf16(kf0, qfA0, sA[mt], 0, 0, 0);
      sA[mt] = __builtin_amdgcn_mfma_f32_16x16x32_bf16(kf1, qfA1, sA[mt], 0, 0, 0);
      sB[mt] = __builtin_amdgcn_mfma_f32_16x16x32_bf16(kf0, qfB0, sB[mt], 0, 0, 0);
      sB[mt] = __builtin_amdgcn_mfma_f32_16x16x32_bf16(kf1, qfB1, sB[mt], 0, 0, 0);
    }
    __builtin_amdgcn_s_setprio(0);

    // ---- p = exp2(s*scale); pack P^T to per-wave LDS (swizzled) ----
#pragma unroll
    for (int mt = 0; mt < 4; ++mt) {
      float e0 = exp2f(sA[mt][0] * SCL2E), e1 = exp2f(sA[mt][1] * SCL2E),
            e2 = exp2f(sA[mt][2] * SCL2E), e3 = exp2f(sA[mt][3] * SCL2E);
      lsumA += (e0 + e1) + (e2 + e3);
      ushort4 oA;
      oA.x = f2bfu(e0); oA.y = f2bfu(e1); oA.z = f2bfu(e2); oA.w = f2bfu(e3);
      *(ushort4*)(qpA + (((mt << 5) + (quad << 3)) ^ fsw)) = oA;
      e0 = exp2f(sB[mt][0] * SCL2E); e1 = exp2f(sB[mt][1] * SCL2E);
      e2 = exp2f(sB[mt][2] * SCL2E); e3 = exp2f(sB[mt][3] * SCL2E);
      lsumB += (e0 + e1) + (e2 + e3);
      ushort4 oB;
      oB.x = f2bfu(e0); oB.y = f2bfu(e1); oB.z = f2bfu(e2); oB.w = f2bfu(e3);
      *(ushort4*)(qpB + (((mt << 5) + (quad << 3)) ^ fsw)) = oB;
    }
    bf16x8 pfA0 = *(const bf16x8*)(qpA + (((quad << 4) +  0) ^ fsw));
    bf16x8 pfA1 = *(const bf16x8*)(qpA + (((quad << 4) + 64) ^ fsw));
    bf16x8 pfB0 = *(const bf16x8*)(qpB + (((quad << 4) +  0) ^ fsw));
    bf16x8 pfB1 = *(const bf16x8*)(qpB + (((quad << 4) + 64) ^ fsw));

    // ---- PV: each vf read feeds 2 MFMAs ----
    __builtin_amdgcn_s_setprio(1);
#pragma unroll
    for (int dt = 0; dt < 4; ++dt) {
      char* vr = (char*)&Vs[cur][dt * 16 + ml][0];
      bf16x8 vf0 = *(const bf16x8*)(vr + (((quad << 4) +  0) ^ fsw));
      bf16x8 vf1 = *(const bf16x8*)(vr + (((quad << 4) + 64) ^ fsw));
      oaccA[dt] = __builtin_amdgcn_mfma_f32_16x16x32_bf16(vf0, pfA0, oaccA[dt], 0, 0, 0);
      oaccA[dt] = __builtin_amdgcn_mfma_f32_16x16x32_bf16(vf1, pfA1, oaccA[dt], 0, 0, 0);
      oaccB[dt] = __builtin_amdgcn_mfma_f32_16x16x32_bf16(vf0, pfB0, oaccB[dt], 0, 0, 0);
      oaccB[dt] = __builtin_amdgcn_mfma_f32_16x16x32_bf16(vf1, pfB1, oaccB[dt], 0, 0, 0);
    }
    __builtin_amdgcn_s_setprio(0);

    __syncthreads();   // readers of buf[cur] done; writes of buf[nxt] visible
  }

  // ---- cross-quad l reduction (lanes with same ml share q) ----
  lsumA += __shfl_xor(lsumA, 16);
  lsumA += __shfl_xor(lsumA, 32);
  lsumB += __shfl_xor(lsumB, 16);
  lsumB += __shfl_xor(lsumB, 32);
  const size_t lbase = (((size_t)(ks * 2 + b)) * NHEAD + h) * S_LEN;
  const size_t obaseA = (lbase + qrA) * DKH;
  const size_t obaseB = (lbase + qrB) * DKH;
#pragma unroll
  for (int dt = 0; dt < 4; ++dt) {
    *(f32x4*)&Opart[obaseA + dt * 16 + (quad << 2)] = oaccA[dt];
    *(f32x4*)&Opart[obaseB + dt * 16 + (quad << 2)] = oaccB[dt];
  }
  if (quad == 0) {
    Lpart[lbase + qrA] = lsumA;
    Lpart[lbase + qrB] = lsumB;
  }
}

// ---------------------------------------------------------------------------
// combine split-K attention partials: O = (O0+O1)/(l0+l1), bf16 [B][S][H*DKH]
// VECTORIZED: float4 partial reads + ushort4 store. 192 active lanes.
// ---------------------------------------------------------------------------
__global__ __launch_bounds__(256) void attn_combine_kernel(
    const float* __restrict__ Op,   // [KSPLIT][B][H][S][DKH]
    const float* __restrict__ Lp,   // [KSPLIT][B][H][S]
    unsigned short* __restrict__ O) // [B][S][DMODEL]
{
  const int s = blockIdx.x & (S_LEN - 1);
  const int b = blockIdx.x >> 11;
  const int tid = threadIdx.x;
  if (tid >= DMODEL / 4) return;    // 192 lanes active
  const size_t ohalf = (size_t)2 * NHEAD * S_LEN * DKH;
  const size_t lhalf = (size_t)2 * NHEAD * S_LEN;
  const int c = tid * 4;
  const int hh = c >> 6, dd = c & 63;
  const size_t li = ((size_t)b * NHEAD + hh) * S_LEN + s;
  const size_t oi = li * DKH + dd;
  float4 o0 = *(const float4*)&Op[oi];
  float4 o1 = *(const float4*)&Op[ohalf + oi];
  const float l = Lp[li] + Lp[lhalf + li];
  ushort4 o;
  o.x = f2bfu((o0.x + o1.x) / l);
  o.y = f2bfu((o0.y + o1.y) / l);
  o.z = f2bfu((o0.z + o1.z) / l);
  o.w = f2bfu((o0.w + o1.w) / l);
  *(ushort4*)&O[((size_t)b * S_LEN + s) * DMODEL + c] = o;
}

// ---------------------------------------------------------------------------
// out = LayerNorm(X + Y [+ Y2]) * w + b; dtype flags (1 = bf16); Y2 nullable.
// VECTORIZED: 192 active lanes x ushort4/float4.
// ---------------------------------------------------------------------------
__global__ __launch_bounds__(256) void add_ln_kernel(
    const void* __restrict__ X, const void* __restrict__ Y,
    const void* __restrict__ Y2,
    const float* __restrict__ w, const float* __restrict__ bvec,
    void* __restrict__ out, int xbf, int ybf, int obf)
{
  __shared__ float buf[DMODEL];
  __shared__ float rbuf[8];
  const int tid  = threadIdx.x;
  const int lane = tid & 63, wv = tid >> 6;
  const size_t base = (size_t)blockIdx.x * DMODEL;
  const int j = tid * 4;            // 192 lanes active (j < 768)

  float v[4];
  float s = 0.f, s2 = 0.f;
  if (j < DMODEL) {
    if (xbf) {
      ushort4 xv = *(const ushort4*)((const unsigned short*)X + base + j);
      v[0] = bfu2f(xv.x); v[1] = bfu2f(xv.y); v[2] = bfu2f(xv.z); v[3] = bfu2f(xv.w);
    } else {
      float4 xv = *(const float4*)((const float*)X + base + j);
      v[0] = xv.x; v[1] = xv.y; v[2] = xv.z; v[3] = xv.w;
    }
    if (ybf) {
      ushort4 yv = *(const ushort4*)((const unsigned short*)Y + base + j);
      v[0] += bfu2f(yv.x); v[1] += bfu2f(yv.y); v[2] += bfu2f(yv.z); v[3] += bfu2f(yv.w);
    } else {
      float4 yv = *(const float4*)((const float*)Y + base + j);
      v[0] += yv.x; v[1] += yv.y; v[2] += yv.z; v[3] += yv.w;
    }
    if (Y2) {
      if (ybf) {
        ushort4 yv = *(const ushort4*)((const unsigned short*)Y2 + base + j);
        v[0] += bfu2f(yv.x); v[1] += bfu2f(yv.y); v[2] += bfu2f(yv.z); v[3] += bfu2f(yv.w);
      } else {
        float4 yv = *(const float4*)((const float*)Y2 + base + j);
        v[0] += yv.x; v[1] += yv.y; v[2] += yv.z; v[3] += yv.w;
      }
    }
#pragma unroll
    for (int k = 0; k < 4; ++k) {
      buf[j + k] = v[k];
      s += v[k]; s2 += v[k] * v[k];
    }
  }
#pragma unroll
  for (int o = 32; o; o >>= 1) { s += __shfl_xor(s, o); s2 += __shfl_xor(s2, o); }
  if (lane == 0) { rbuf[wv] = s; rbuf[4 + wv] = s2; }
  __syncthreads();
  const float S  = rbuf[0] + rbuf[1] + rbuf[2] + rbuf[3];
  const float S2 = rbuf[4] + rbuf[5] + rbuf[6] + rbuf[7];
  const float mean = S * (1.f / (float)DMODEL);
  const float var  = S2 * (1.f / (float)DMODEL) - mean * mean;
  const float rstd = rsqrtf(var + 1e-5f);
  if (j < DMODEL) {
    float o[4];
#pragma unroll
    for (int k = 0; k < 4; ++k)
      o[k] = (buf[j + k] - mean) * rstd * w[j + k] + bvec[j + k];
    if (obf) {
      ushort4 ov;
      ov.x = f2bfu(o[0]); ov.y = f2bfu(o[1]); ov.z = f2bfu(o[2]); ov.w = f2bfu(o[3]);
      *(ushort4*)((unsigned short*)out + base + j) = ov;
    } else {
      float4 ov;
      ov.x = o[0]; ov.y = o[1]; ov.z = o[2]; ov.w = o[3];
      *(float4*)((float*)out + base + j) = ov;
    }
  }
}

// ---------------------------------------------------------------------------
extern "C" void kernel_launch(void* const* d_in, const int* in_sizes, int n_in,
                              void* d_out, int out_size, void* d_ws, size_t ws_size,
                              hipStream_t stream) {
  const float* src  = (const float*)d_in[0];
  const float* Wq   = (const float*)d_in[1];
  const float* bq   = (const float*)d_in[2];
  const float* Wk   = (const float*)d_in[3];
  const float* bk   = (const float*)d_in[4];
  const float* Wv   = (const float*)d_in[5];
  const float* bv   = (const float*)d_in[6];
  const float* Wo   = (const float*)d_in[7];
  const float* bo   = (const float*)d_in[8];
  const float* ln1w = (const float*)d_in[9];
  const float* ln1b = (const float*)d_in[10];
  const float* W1   = (const float*)d_in[11];
  const float* b1   = (const float*)d_in[12];
  const float* W2   = (const float*)d_in[13];
  const float* b2   = (const float*)d_in[14];
  const float* ln2w = (const float*)d_in[15];
  const float* ln2b = (const float*)d_in[16];
  (void)ws_size; (void)in_sizes; (void)n_in; (void)out_size;

  unsigned short* p = (unsigned short*)d_ws;
  const size_t SEG = (size_t)MROWS * DMODEL;
  unsigned short* srcb = p; p += SEG;
  unsigned short* qb   = p; p += SEG;   // Q; later split-K partial z0
  unsigned short* kb_  = p; p += SEG;   // K; later x1
  unsigned short* vbT  = p; p += SEG;   // V^T; later split-K partial z1
  unsigned short* ctx  = p; p += SEG;
  unsigned short* ff   = p; p += (size_t)MROWS * DFF_K;
  unsigned short* wqt  = p; p += (size_t)DMODEL * DMODEL;
  unsigned short* wkt  = p; p += (size_t)DMODEL * DMODEL;
  unsigned short* wvt  = p; p += (size_t)DMODEL * DMODEL;
  unsigned short* wot  = p; p += (size_t)DMODEL * DMODEL;
  unsigned short* w1t  = p; p += (size_t)DMODEL * DFF_K;
  unsigned short* w2t  = p; p += (size_t)DMODEL * DFF_K;
  unsigned short* x1 = kb_;
  // attention split-K scratch (regions dead during attention):
  //   ff  (25.17 MB) exactly fits [KSPLIT][B][H][S][DKH] f32 O-partials
  //   wqt (1.18 MB)  holds [KSPLIT][B][H][S] f32 l-partials (393 KB)
  float* opart = (float*)ff;
  float* lpart = (float*)wqt;

  dim3 blk(256);

  // 0: conversions
  convert_kernel<<<dim3(SEG / 1024), blk, 0, stream>>>(src, srcb, (int)(SEG / 4));
  transpose_conv4_kernel<<<dim3(12, 12, 4), blk, 0, stream>>>(
      Wq, Wk, Wv, Wo, wqt, wkt, wvt, wot);
  transpose_conv_kernel<<<dim3(12, 48), blk, 0, stream>>>(W1, w1t, DMODEL, DFF_K, 0);
  transpose_conv_kernel<<<dim3(48, 12), blk, 0, stream>>>(W2, w2t, DFF_K, DMODEL, 0);

  // 1: fused QKV projections (BN=128, 576 blocks; V written transposed)
  dim3 gqkv(MROWS / 128, DMODEL / 128, 3);     // 32 x 6 x 3
  qkv_gemm_kernel<<<gqkv, blk, 0, stream>>>(srcb, wqt, wkt, wvt, bq, bk, bv,
                                            qb, kb_, vbT);

  // 2: MFMA flash attention v4 (dbuf K/V, 1 barrier/tile) -> f32 partials
  dim3 ga(NHEAD, 2, (S_LEN / 128) * KSPLIT);   // 12 x 2 x 32 = 768 blocks
  flash_attn_mfma<<<ga, blk, 0, stream>>>(qb, kb_, vbT, opart, lpart);
  attn_combine_kernel<<<dim3(MROWS), blk, 0, stream>>>(opart, lpart, ctx);

  // 3: attn_out partials = ctx @ Wo + bo, BN=64 split-K=2 -> qb (z0), vbT (z1)
  dim3 gWo(MROWS / 128, DMODEL / 64, 2);       // 32 x 12 x 2 = 768
  mfma_gemm_kernel<64><<<gWo, blk, 0, stream>>>(ctx, wot, bo, qb,
                                                DMODEL, DMODEL, 0, DMODEL / 2, 2 * SEG);

  // 4: x1 = LN(srcb + p0 + p1)
  add_ln_kernel<<<dim3(MROWS), blk, 0, stream>>>(srcb, qb, vbT,
                                                 ln1w, ln1b, x1, 1, 1, 1);

  // 5: ff = relu(x1 @ W1 + b1)  (BN=128, 768 blocks)
  dim3 gF1(MROWS / 128, DFF_K / 128, 1);       // 32 x 24
  mfma_gemm_kernel<128><<<gF1, blk, 0, stream>>>(x1, w1t, b1, ff,
                                                 DMODEL, DFF_K, 1, DMODEL, 0);

  // 6: y2 partials = ff @ W2 + b2, BN=64 split-K=2 -> qb (z0), vbT (z1)
  dim3 gW2(MROWS / 128, DMODEL / 64, 2);       // 32 x 12 x 2 = 768
  mfma_gemm_kernel<64><<<gW2, blk, 0, stream>>>(ff, w2t, b2, qb,
                                                DFF_K, DMODEL, 0, DFF_K / 2, 2 * SEG);

  // 7: out = LN(x1 + p0 + p1)
  add_ln_kernel<<<dim3(MROWS), blk, 0, stream>>>(x1, qb, vbT,
                                                 ln2w, ln2b, (float*)d_out, 1, 1, 0);
}

// Round 14
// 273.271 us; speedup vs baseline: 1.4067x; 1.0153x over previous
//
#include <hip/hip_runtime.h>
#include <hip/hip_bf16.h>

#define S_LEN 2048
#define DMODEL 768
#define NHEAD 12
#define DKH 64
#define DFF_K 3072
#define MROWS 4096   // B*S
#define KSPLIT 2
#define KHALF (S_LEN / KSPLIT)

typedef __attribute__((ext_vector_type(8))) short bf16x8;
typedef __attribute__((ext_vector_type(8))) unsigned short us8;
typedef __attribute__((ext_vector_type(4))) float f32x4;

__device__ __forceinline__ float bfu2f(unsigned short u) {
  return __uint_as_float(((unsigned int)u) << 16);
}
__device__ __forceinline__ unsigned short f2bfu(float f) {
  __hip_bfloat16 h = __float2bfloat16(f);
  return *reinterpret_cast<unsigned short*>(&h);
}

// async global->LDS 16B: LDS dest is wave-uniform base + lane*16 (HW rule)
__device__ __forceinline__ void async16(const unsigned short* g, unsigned short* l) {
  __builtin_amdgcn_global_load_lds(
      (const __attribute__((address_space(1))) unsigned int*)g,
      (__attribute__((address_space(3))) unsigned int*)l, 16, 0, 0);
}

// ---------------------------------------------------------------------------
// fp32 [R][C] -> bf16 [C][R] transpose-convert body (generic, head or flat).
// ---------------------------------------------------------------------------
__device__ __forceinline__ void transpose_conv_body(
    const float* in, unsigned short* out, int R, int Ctot, int head,
    int bx, int by, int tid)
{
  __shared__ float t[64][68];
  const int r0 = bx * 64;
  const int c0 = by * 64;
  const float* ib;
  int ld;
  if (head) { ib = in + (size_t)by * R * 64; ld = 64; }
  else      { ib = in + c0;                  ld = Ctot; }
  const int lr = tid >> 4;
  const int lc = (tid & 15) << 2;

#pragma unroll
  for (int rr = 0; rr < 4; ++rr) {
    const int row = rr * 16 + lr;
    float4 v = *(const float4*)(ib + (size_t)(r0 + row) * ld + lc);
    t[row][lc + 0] = v.x; t[row][lc + 1] = v.y;
    t[row][lc + 2] = v.z; t[row][lc + 3] = v.w;
  }
  __syncthreads();
#pragma unroll
  for (int rr = 0; rr < 4; ++rr) {
    const int oc = rr * 16 + lr;
    ushort4 o;
    o.x = f2bfu(t[lc + 0][oc]); o.y = f2bfu(t[lc + 1][oc]);
    o.z = f2bfu(t[lc + 2][oc]); o.w = f2bfu(t[lc + 3][oc]);
    *(ushort4*)(out + (size_t)(c0 + oc) * R + r0 + lc) = o;
  }
}

// ---------------------------------------------------------------------------
// FUSED prep: one launch replaces convert + transpose_conv4 + 2x transpose.
// Linearized grid (4800 blocks):
//   [0,3072)        src fp32 -> bf16 convert (1024 elems/block)
//   [3072,3648)     Wq/Wk/Wv (head) + Wo (flat) 64x64 transpose tiles (z*144)
//   [3648,4224)     W1 transpose tiles (12 x 48)
//   [4224,4800)     W2 transpose tiles (48 x 12)
// Bodies byte-identical to the previous separate kernels.
// ---------------------------------------------------------------------------
__global__ __launch_bounds__(256) void prep_kernel(
    const float* __restrict__ src, unsigned short* __restrict__ srcb,
    const float* __restrict__ Wq, const float* __restrict__ Wk,
    const float* __restrict__ Wv, const float* __restrict__ Wo,
    unsigned short* __restrict__ wqt, unsigned short* __restrict__ wkt,
    unsigned short* __restrict__ wvt, unsigned short* __restrict__ wot,
    const float* __restrict__ W1, unsigned short* __restrict__ w1t,
    const float* __restrict__ W2, unsigned short* __restrict__ w2t)
{
  const int tid = threadIdx.x;
  const int idx = blockIdx.x;
  if (idx < 3072) {                    // convert: 3072 x 1024 = MROWS*DMODEL
    const int i = idx * 256 + tid;
    float4 v = *(const float4*)(src + (size_t)i * 4);
    ushort4 o;
    o.x = f2bfu(v.x); o.y = f2bfu(v.y); o.z = f2bfu(v.z); o.w = f2bfu(v.w);
    *(ushort4*)(srcb + (size_t)i * 4) = o;
    return;
  }
  int t = idx - 3072;
  if (t < 576) {                       // Wq/Wk/Wv/Wo: z = t/144, 12x12 tiles
    const int z = t / 144, r = t % 144;
    const int bx = r % 12, by = r / 12;
    const float* in = (z == 0) ? Wq : (z == 1) ? Wk : (z == 2) ? Wv : Wo;
    unsigned short* out = (z == 0) ? wqt : (z == 1) ? wkt : (z == 2) ? wvt : wot;
    transpose_conv_body(in, out, DMODEL, DMODEL, (z < 3) ? 1 : 0, bx, by, tid);
    return;
  }
  t -= 576;
  if (t < 576) {                       // W1: dim (12, 48)
    transpose_conv_body(W1, w1t, DMODEL, DFF_K, 0, t % 12, t / 12, tid);
    return;
  }
  t -= 576;                            // W2: dim (48, 12)
  transpose_conv_body(W2, w2t, DFF_K, DMODEL, 0, t % 48, t / 48, tid);
}

// ---------------------------------------------------------------------------
// Stage one BK=64 tile pair (A: 128 rows, B: BN rows, 64 cols bf16) into
// linear LDS via global_load_lds width-16. Global source is inverse-XOR-
// swizzled (slot ^= row&7) so that swizzled ds_reads see linear data.
// Per-thread instruction count: 4 + BN/32 (6 for BN=64, 8 for BN=128).
// ---------------------------------------------------------------------------
template<int BN>
__device__ __forceinline__ void stage_tile(
    const unsigned short* __restrict__ Ab,   // A + row0*K (+0), element ptr
    const unsigned short* __restrict__ Bb,   // BT + col0*K
    unsigned short* As, unsigned short* Bs,  // LDS linear [rows][64]
    int wid, int lane, int K, int kofs)      // kofs in elements
{
  const int r = lane >> 3;
  const int s = lane & 7;
#pragma unroll
  for (int p = 0; p < 4; ++p) {
    const int row = wid * 32 + p * 8 + r;
    async16(Ab + (size_t)row * K + kofs + ((s ^ (row & 7)) << 3),
            As + (size_t)(wid * 32 + p * 8) * 64);
  }
#pragma unroll
  for (int p = 0; p < BN / 32; ++p) {
    const int row = wid * (BN / 4) + p * 8 + r;
    async16(Bb + (size_t)row * K + kofs + ((s ^ (row & 7)) << 3),
            Bs + (size_t)(wid * (BN / 4) + p * 8) * 64);
  }
}

// ---------------------------------------------------------------------------
// MFMA bf16 GEMM, BK=64, double-buffered LDS filled by global_load_lds,
// XOR-swizzled reads, COUNTED-vmcnt pipeline (proven round-5 structure).
// C = act(A[M x K] @ BT[N x K]^T + bias). BM=128, BN template (64 or 128).
// Grid: x = M row-block, y = N col-block, z = K-split
// (partial z -> C + z*out_stride; bias from z==0 only).
// ---------------------------------------------------------------------------
template<int BN>
__global__ __launch_bounds__(256) void mfma_gemm_kernel(
    const unsigned short* __restrict__ A,
    const unsigned short* __restrict__ BT,
    const float* __restrict__ bias,
    unsigned short* __restrict__ C,
    int K, int N, int relu, int klen, size_t out_stride)
{
  constexpr int WN = (BN == 128) ? 64 : 32;
  constexpr int NJ = WN / 16;
  __shared__ unsigned short As[2][128][64];
  __shared__ unsigned short Bs[2][BN][64];

  const int tid  = threadIdx.x;
  const int wid  = tid >> 6;
  const int lane = tid & 63;
  const int ml   = lane & 15;
  const int quad = lane >> 4;
  const int wm   = (wid & 1) * 64;
  const int wn   = (wid >> 1) * WN;
  const int row0 = blockIdx.x * 128;
  const int col0 = blockIdx.y * BN;
  const int zed  = blockIdx.z;
  const int kb0  = zed * klen;
  const int nsteps = klen >> 6;
  const int fsw = (ml & 7) << 4;   // fragment-read swizzle (row&7 == ml&7)

  const unsigned short* Ab = A  + (size_t)row0 * K + kb0;
  const unsigned short* Bb = BT + (size_t)col0 * K + kb0;

  f32x4 acc[4][NJ];
#pragma unroll
  for (int i = 0; i < 4; ++i)
#pragma unroll
    for (int j = 0; j < NJ; ++j)
#pragma unroll
      for (int r = 0; r < 4; ++r) acc[i][j][r] = 0.f;

  stage_tile<BN>(Ab, Bb, &As[0][0][0], &Bs[0][0][0], wid, lane, K, 0);

  for (int st = 0; st < nsteps; ++st) {
    const int cur = st & 1;
    if (st + 1 < nsteps) {
      stage_tile<BN>(Ab, Bb, &As[cur ^ 1][0][0], &Bs[cur ^ 1][0][0],
                     wid, lane, K, (st + 1) << 6);
      if constexpr (BN == 128) { asm volatile("s_waitcnt vmcnt(8)" ::: "memory"); }
      else                     { asm volatile("s_waitcnt vmcnt(6)" ::: "memory"); }
    } else {
      asm volatile("s_waitcnt vmcnt(0)" ::: "memory");
    }
    __builtin_amdgcn_s_barrier();   // all waves: stage(t) landed in LDS

    const char* Ac = (const char*)&As[cur][0][0];
    const char* Bc = (const char*)&Bs[cur][0][0];
#pragma unroll
    for (int h = 0; h < 2; ++h) {
      bf16x8 af[4], bfr[NJ];
#pragma unroll
      for (int i = 0; i < 4; ++i) {
        const int ar = wm + i * 16 + ml;
        af[i] = *(const bf16x8*)(Ac + ar * 128 + (((h << 6) + (quad << 4)) ^ fsw));
      }
#pragma unroll
      for (int j = 0; j < NJ; ++j) {
        const int br = wn + j * 16 + ml;
        bfr[j] = *(const bf16x8*)(Bc + br * 128 + (((h << 6) + (quad << 4)) ^ fsw));
      }
#pragma unroll
      for (int i = 0; i < 4; ++i)
#pragma unroll
        for (int j = 0; j < NJ; ++j)
          acc[i][j] = __builtin_amdgcn_mfma_f32_16x16x32_bf16(
              af[i], bfr[j], acc[i][j], 0, 0, 0);
    }
    __builtin_amdgcn_s_barrier();   // readers of buf[cur] done
  }

  unsigned short* Cz = C + (size_t)zed * out_stride;
#pragma unroll
  for (int j = 0; j < NJ; ++j) {
    const int col = col0 + wn + j * 16 + ml;
    const float bb = (zed == 0) ? bias[col] : 0.f;
#pragma unroll
    for (int i = 0; i < 4; ++i) {
      const int r0g = row0 + wm + i * 16 + (quad << 2);
#pragma unroll
      for (int r = 0; r < 4; ++r) {
        float v = acc[i][j][r] + bb;
        if (relu) v = fmaxf(v, 0.f);
        Cz[(size_t)(r0g + r) * N + col] = f2bfu(v);
      }
    }
  }
}

// fused QKV projection, BN=128 (proven round-13: -3.5us vs BN=64).
// 576 blocks (32 x 6 x 3), 64KB LDS -> 2 blocks/CU. z=0 -> Q, z=1 -> K,
// z=2 -> V (VT store). BK=64 gload_lds staging + counted vmcnt.
__global__ __launch_bounds__(256) void qkv_gemm_kernel(
    const unsigned short* __restrict__ A,
    const unsigned short* __restrict__ W0, const unsigned short* __restrict__ W1,
    const unsigned short* __restrict__ W2,
    const float* __restrict__ bq, const float* __restrict__ bk,
    const float* __restrict__ bv,
    unsigned short* __restrict__ C0, unsigned short* __restrict__ C1,
    unsigned short* __restrict__ C2)
{
  __shared__ unsigned short As[2][128][64];
  __shared__ unsigned short Bs[2][128][64];
  const int z = blockIdx.z;
  const unsigned short* BT = (z == 0) ? W0 : (z == 1) ? W1 : W2;
  const float* bias = (z == 0) ? bq : (z == 1) ? bk : bv;
  unsigned short* C = (z == 0) ? C0 : (z == 1) ? C1 : C2;
  const int K = DMODEL, N = DMODEL;

  const int tid  = threadIdx.x;
  const int wid  = tid >> 6;
  const int lane = tid & 63;
  const int ml   = lane & 15;
  const int quad = lane >> 4;
  const int wm   = (wid & 1) * 64;
  const int wn   = (wid >> 1) * 64;
  const int row0 = blockIdx.x * 128;
  const int col0 = blockIdx.y * 128;
  const int fsw = (ml & 7) << 4;

  const unsigned short* Ab = A  + (size_t)row0 * K;
  const unsigned short* Bb = BT + (size_t)col0 * K;

  f32x4 acc[4][4];
#pragma unroll
  for (int i = 0; i < 4; ++i)
#pragma unroll
    for (int j = 0; j < 4; ++j)
#pragma unroll
      for (int r = 0; r < 4; ++r) acc[i][j][r] = 0.f;

  stage_tile<128>(Ab, Bb, &As[0][0][0], &Bs[0][0][0], wid, lane, K, 0);

  const int nsteps = K >> 6;   // 12
  for (int st = 0; st < nsteps; ++st) {
    const int cur = st & 1;
    if (st + 1 < nsteps) {
      stage_tile<128>(Ab, Bb, &As[cur ^ 1][0][0], &Bs[cur ^ 1][0][0],
                      wid, lane, K, (st + 1) << 6);
      asm volatile("s_waitcnt vmcnt(8)" ::: "memory");
    } else {
      asm volatile("s_waitcnt vmcnt(0)" ::: "memory");
    }
    __builtin_amdgcn_s_barrier();

    const char* Ac = (const char*)&As[cur][0][0];
    const char* Bc = (const char*)&Bs[cur][0][0];
#pragma unroll
    for (int h = 0; h < 2; ++h) {
      bf16x8 af[4], bfr[4];
#pragma unroll
      for (int i = 0; i < 4; ++i) {
        const int ar = wm + i * 16 + ml;
        af[i] = *(const bf16x8*)(Ac + ar * 128 + (((h << 6) + (quad << 4)) ^ fsw));
      }
#pragma unroll
      for (int j = 0; j < 4; ++j) {
        const int br = wn + j * 16 + ml;
        bfr[j] = *(const bf16x8*)(Bc + br * 128 + (((h << 6) + (quad << 4)) ^ fsw));
      }
#pragma unroll
      for (int i = 0; i < 4; ++i)
#pragma unroll
        for (int j = 0; j < 4; ++j)
          acc[i][j] = __builtin_amdgcn_mfma_f32_16x16x32_bf16(
              af[i], bfr[j], acc[i][j], 0, 0, 0);
    }
    __builtin_amdgcn_s_barrier();
  }

#pragma unroll
  for (int j = 0; j < 4; ++j) {
    const int col = col0 + wn + j * 16 + ml;
    const float bb = bias[col];
#pragma unroll
    for (int i = 0; i < 4; ++i) {
      const int r0g = row0 + wm + i * 16 + (quad << 2);
      if (z == 2) {
        const int bb_ = r0g >> 11, s = r0g & 2047;
        const int hh = col >> 6, dd = col & 63;
        ushort4 o;
        o.x = f2bfu(acc[i][j][0] + bb); o.y = f2bfu(acc[i][j][1] + bb);
        o.z = f2bfu(acc[i][j][2] + bb); o.w = f2bfu(acc[i][j][3] + bb);
        *(ushort4*)(C + ((size_t)((bb_ * NHEAD + hh) * DKH + dd)) * S_LEN + s) = o;
      } else {
#pragma unroll
        for (int r = 0; r < 4; ++r)
          C[(size_t)(r0g + r) * N + col] = f2bfu(acc[i][j][r] + bb);
      }
    }
  }
}

// ---------------------------------------------------------------------------
// MFMA flash attention v4 (proven 51.6-53.3us floor; v5/v6/v6b all worse):
// 2 q-subtiles per wave, K/V LDS double-buffer, ONE barrier per tile, XOR
// swizzle, setprio around MFMA clusters, 48KB LDS, launch_bounds(256,3).
// Grid: x = head, y = batch, z = qtile128*KSPLIT + split.
// ---------------------------------------------------------------------------
#define SCL2E 0.1803368822f   // 0.125 * log2(e)
__global__ __launch_bounds__(256, 3) void flash_attn_mfma(
    const unsigned short* __restrict__ Q,
    const unsigned short* __restrict__ K,
    const unsigned short* __restrict__ VT,
    float* __restrict__ Opart,      // [KSPLIT][B][H][S][DKH] f32, unnormalized
    float* __restrict__ Lpart)      // [KSPLIT][B][H][S] f32
{
  __shared__ unsigned short Ks[2][64][64];
  __shared__ unsigned short Vs[2][64][64];     // VT tile: [d][t_local]
  __shared__ unsigned short QP[4][2][16][64];  // per-wave, per-subtile P^T

  const int tid  = threadIdx.x;
  const int wid  = tid >> 6;
  const int lane = tid & 63;
  const int ml   = lane & 15;
  const int quad = lane >> 4;
  const int h    = blockIdx.x, b = blockIdx.y;
  const int q0   = (blockIdx.z >> 1) * 128;
  const int ks   = blockIdx.z & 1;
  const int kt0  = ks * KHALF;

  const size_t qkbase = ((size_t)b * S_LEN) * DMODEL + (size_t)h * DKH;
  const size_t vtbase = ((size_t)(b * NHEAD + h)) * DKH * S_LEN;

  const int sr  = tid >> 2;          // 0..63 staging row
  const int scb = (tid & 3) << 5;    // staging byte col: 0,32,64,96
  const int ssw = (sr & 7) << 4;     // staging swizzle
  const int fsw = (ml & 7) << 4;     // fragment-row swizzle (row&7 == ml&7)

  // ---- Q fragments direct from global (once per block) ----
  const int qrA = q0 + wid * 32 + ml;
  const int qrB = qrA + 16;
  const unsigned short* qpg = Q + qkbase;
  bf16x8 qfA0 = *(const bf16x8*)(qpg + (size_t)qrA * DMODEL + (quad << 3));
  bf16x8 qfA1 = *(const bf16x8*)(qpg + (size_t)qrA * DMODEL + 32 + (quad << 3));
  bf16x8 qfB0 = *(const bf16x8*)(qpg + (size_t)qrB * DMODEL + (quad << 3));
  bf16x8 qfB1 = *(const bf16x8*)(qpg + (size_t)qrB * DMODEL + 32 + (quad << 3));

  const unsigned short* pK = K + qkbase + (size_t)(kt0 + sr) * DMODEL + (scb >> 1);
  const unsigned short* pV = VT + vtbase + (size_t)sr * S_LEN + kt0 + (scb >> 1);

  float lsumA = 0.f, lsumB = 0.f;
  f32x4 oaccA[4], oaccB[4];
#pragma unroll
  for (int dt = 0; dt < 4; ++dt)
#pragma unroll
    for (int r = 0; r < 4; ++r) { oaccA[dt][r] = 0.f; oaccB[dt][r] = 0.f; }

  char* qpA = (char*)&QP[wid][0][ml][0];
  char* qpB = (char*)&QP[wid][1][ml][0];

  // ---- prologue: tile0 -> regs -> buf0; tile1 -> regs; barrier ----
  us8 rk0 = *(const us8*)(pK);
  us8 rk1 = *(const us8*)(pK + 8);
  us8 rv0 = *(const us8*)(pV);
  us8 rv1 = *(const us8*)(pV + 8);
  {
    char* kw = (char*)&Ks[0][sr][0];
    char* vw = (char*)&Vs[0][sr][0];
    *(us8*)(kw + ((scb +  0) ^ ssw)) = rk0;
    *(us8*)(kw + ((scb + 16) ^ ssw)) = rk1;
    *(us8*)(vw + ((scb +  0) ^ ssw)) = rv0;
    *(us8*)(vw + ((scb + 16) ^ ssw)) = rv1;
  }
  rk0 = *(const us8*)(pK + (size_t)64 * DMODEL);
  rk1 = *(const us8*)(pK + (size_t)64 * DMODEL + 8);
  rv0 = *(const us8*)(pV + 64);
  rv1 = *(const us8*)(pV + 64 + 8);
  __syncthreads();

  const int NT = KHALF / 64;   // 16
  for (int t = 0; t < NT; ++t) {
    const int cur = t & 1;
    if (t + 1 < NT) {
      // write tile t+1 (in regs) into buf[cur^1]; overlaps with compute below
      char* kw = (char*)&Ks[cur ^ 1][sr][0];
      char* vw = (char*)&Vs[cur ^ 1][sr][0];
      *(us8*)(kw + ((scb +  0) ^ ssw)) = rk0;
      *(us8*)(kw + ((scb + 16) ^ ssw)) = rk1;
      *(us8*)(vw + ((scb +  0) ^ ssw)) = rv0;
      *(us8*)(vw + ((scb + 16) ^ ssw)) = rv1;
      if (t + 2 < NT) {              // prefetch tile t+2 into regs
        const size_t ko = (size_t)(t + 2) * 64;
        rk0 = *(const us8*)(pK + ko * DMODEL);
        rk1 = *(const us8*)(pK + ko * DMODEL + 8);
        rv0 = *(const us8*)(pV + ko);
        rv1 = *(const us8*)(pV + ko + 8);
      }
    }

    // ---- S^T tile for both q-subtiles: each kf read feeds 2 MFMAs ----
    f32x4 sA[4], sB[4];
#pragma unroll
    for (int mt = 0; mt < 4; ++mt)
#pragma unroll
      for (int r = 0; r < 4; ++r) { sA[mt][r] = 0.f; sB[mt][r] = 0.f; }
    __builtin_amdgcn_s_setprio(1);
#pragma unroll
    for (int mt = 0; mt < 4; ++mt) {
      char* kr = (char*)&Ks[cur][mt * 16 + ml][0];
      bf16x8 kf0 = *(const bf16x8*)(kr + (((quad << 4) +  0) ^ fsw));
      bf16x8 kf1 = *(const bf16x8*)(kr + (((quad << 4) + 64) ^ fsw));
      sA[mt] = __builtin_amdgcn_mfma_f32_16x16x32_bf16(kf0, qfA0, sA[mt], 0, 0, 0);
      sA[mt] = __builtin_amdgcn_mfma_f32_16x16x32_bf16(kf1, qfA1, sA[mt], 0, 0, 0);
      sB[mt] = __builtin_amdgcn_mfma_f32_16x16x32_bf16(kf0, qfB0, sB[mt], 0, 0, 0);
      sB[mt] = __builtin_amdgcn_mfma_f32_16x16x32_bf16(kf1, qfB1, sB[mt], 0, 0, 0);
    }
    __builtin_amdgcn_s_setprio(0);

    // ---- p = exp2(s*scale); pack P^T to per-wave LDS (swizzled) ----
#pragma unroll
    for (int mt = 0; mt < 4; ++mt) {
      float e0 = exp2f(sA[mt][0] * SCL2E), e1 = exp2f(sA[mt][1] * SCL2E),
            e2 = exp2f(sA[mt][2] * SCL2E), e3 = exp2f(sA[mt][3] * SCL2E);
      lsumA += (e0 + e1) + (e2 + e3);
      ushort4 oA;
      oA.x = f2bfu(e0); oA.y = f2bfu(e1); oA.z = f2bfu(e2); oA.w = f2bfu(e3);
      *(ushort4*)(qpA + (((mt << 5) + (quad << 3)) ^ fsw)) = oA;
      e0 = exp2f(sB[mt][0] * SCL2E); e1 = exp2f(sB[mt][1] * SCL2E);
      e2 = exp2f(sB[mt][2] * SCL2E); e3 = exp2f(sB[mt][3] * SCL2E);
      lsumB += (e0 + e1) + (e2 + e3);
      ushort4 oB;
      oB.x = f2bfu(e0); oB.y = f2bfu(e1); oB.z = f2bfu(e2); oB.w = f2bfu(e3);
      *(ushort4*)(qpB + (((mt << 5) + (quad << 3)) ^ fsw)) = oB;
    }
    bf16x8 pfA0 = *(const bf16x8*)(qpA + (((quad << 4) +  0) ^ fsw));
    bf16x8 pfA1 = *(const bf16x8*)(qpA + (((quad << 4) + 64) ^ fsw));
    bf16x8 pfB0 = *(const bf16x8*)(qpB + (((quad << 4) +  0) ^ fsw));
    bf16x8 pfB1 = *(const bf16x8*)(qpB + (((quad << 4) + 64) ^ fsw));

    // ---- PV: each vf read feeds 2 MFMAs ----
    __builtin_amdgcn_s_setprio(1);
#pragma unroll
    for (int dt = 0; dt < 4; ++dt) {
      char* vr = (char*)&Vs[cur][dt * 16 + ml][0];
      bf16x8 vf0 = *(const bf16x8*)(vr + (((quad << 4) +  0) ^ fsw));
      bf16x8 vf1 = *(const bf16x8*)(vr + (((quad << 4) + 64) ^ fsw));
      oaccA[dt] = __builtin_amdgcn_mfma_f32_16x16x32_bf16(vf0, pfA0, oaccA[dt], 0, 0, 0);
      oaccA[dt] = __builtin_amdgcn_mfma_f32_16x16x32_bf16(vf1, pfA1, oaccA[dt], 0, 0, 0);
      oaccB[dt] = __builtin_amdgcn_mfma_f32_16x16x32_bf16(vf0, pfB0, oaccB[dt], 0, 0, 0);
      oaccB[dt] = __builtin_amdgcn_mfma_f32_16x16x32_bf16(vf1, pfB1, oaccB[dt], 0, 0, 0);
    }
    __builtin_amdgcn_s_setprio(0);

    __syncthreads();   // readers of buf[cur] done; writes of buf[nxt] visible
  }

  // ---- cross-quad l reduction (lanes with same ml share q) ----
  lsumA += __shfl_xor(lsumA, 16);
  lsumA += __shfl_xor(lsumA, 32);
  lsumB += __shfl_xor(lsumB, 16);
  lsumB += __shfl_xor(lsumB, 32);
  const size_t lbase = (((size_t)(ks * 2 + b)) * NHEAD + h) * S_LEN;
  const size_t obaseA = (lbase + qrA) * DKH;
  const size_t obaseB = (lbase + qrB) * DKH;
#pragma unroll
  for (int dt = 0; dt < 4; ++dt) {
    *(f32x4*)&Opart[obaseA + dt * 16 + (quad << 2)] = oaccA[dt];
    *(f32x4*)&Opart[obaseB + dt * 16 + (quad << 2)] = oaccB[dt];
  }
  if (quad == 0) {
    Lpart[lbase + qrA] = lsumA;
    Lpart[lbase + qrB] = lsumB;
  }
}

// ---------------------------------------------------------------------------
// combine split-K attention partials: O = (O0+O1)/(l0+l1), bf16 [B][S][H*DKH]
// VECTORIZED: float4 partial reads + ushort4 store. 192 active lanes.
// ---------------------------------------------------------------------------
__global__ __launch_bounds__(256) void attn_combine_kernel(
    const float* __restrict__ Op,   // [KSPLIT][B][H][S][DKH]
    const float* __restrict__ Lp,   // [KSPLIT][B][H][S]
    unsigned short* __restrict__ O) // [B][S][DMODEL]
{
  const int s = blockIdx.x & (S_LEN - 1);
  const int b = blockIdx.x >> 11;
  const int tid = threadIdx.x;
  if (tid >= DMODEL / 4) return;    // 192 lanes active
  const size_t ohalf = (size_t)2 * NHEAD * S_LEN * DKH;
  const size_t lhalf = (size_t)2 * NHEAD * S_LEN;
  const int c = tid * 4;
  const int hh = c >> 6, dd = c & 63;
  const size_t li = ((size_t)b * NHEAD + hh) * S_LEN + s;
  const size_t oi = li * DKH + dd;
  float4 o0 = *(const float4*)&Op[oi];
  float4 o1 = *(const float4*)&Op[ohalf + oi];
  const float l = Lp[li] + Lp[lhalf + li];
  ushort4 o;
  o.x = f2bfu((o0.x + o1.x) / l);
  o.y = f2bfu((o0.y + o1.y) / l);
  o.z = f2bfu((o0.z + o1.z) / l);
  o.w = f2bfu((o0.w + o1.w) / l);
  *(ushort4*)&O[((size_t)b * S_LEN + s) * DMODEL + c] = o;
}

// ---------------------------------------------------------------------------
// out = LayerNorm(X + Y [+ Y2]) * w + b; dtype flags (1 = bf16); Y2 nullable.
// VECTORIZED: 192 active lanes x ushort4/float4.
// ---------------------------------------------------------------------------
__global__ __launch_bounds__(256) void add_ln_kernel(
    const void* __restrict__ X, const void* __restrict__ Y,
    const void* __restrict__ Y2,
    const float* __restrict__ w, const float* __restrict__ bvec,
    void* __restrict__ out, int xbf, int ybf, int obf)
{
  __shared__ float buf[DMODEL];
  __shared__ float rbuf[8];
  const int tid  = threadIdx.x;
  const int lane = tid & 63, wv = tid >> 6;
  const size_t base = (size_t)blockIdx.x * DMODEL;
  const int j = tid * 4;            // 192 lanes active (j < 768)

  float v[4];
  float s = 0.f, s2 = 0.f;
  if (j < DMODEL) {
    if (xbf) {
      ushort4 xv = *(const ushort4*)((const unsigned short*)X + base + j);
      v[0] = bfu2f(xv.x); v[1] = bfu2f(xv.y); v[2] = bfu2f(xv.z); v[3] = bfu2f(xv.w);
    } else {
      float4 xv = *(const float4*)((const float*)X + base + j);
      v[0] = xv.x; v[1] = xv.y; v[2] = xv.z; v[3] = xv.w;
    }
    if (ybf) {
      ushort4 yv = *(const ushort4*)((const unsigned short*)Y + base + j);
      v[0] += bfu2f(yv.x); v[1] += bfu2f(yv.y); v[2] += bfu2f(yv.z); v[3] += bfu2f(yv.w);
    } else {
      float4 yv = *(const float4*)((const float*)Y + base + j);
      v[0] += yv.x; v[1] += yv.y; v[2] += yv.z; v[3] += yv.w;
    }
    if (Y2) {
      if (ybf) {
        ushort4 yv = *(const ushort4*)((const unsigned short*)Y2 + base + j);
        v[0] += bfu2f(yv.x); v[1] += bfu2f(yv.y); v[2] += bfu2f(yv.z); v[3] += bfu2f(yv.w);
      } else {
        float4 yv = *(const float4*)((const float*)Y2 + base + j);
        v[0] += yv.x; v[1] += yv.y; v[2] += yv.z; v[3] += yv.w;
      }
    }
#pragma unroll
    for (int k = 0; k < 4; ++k) {
      buf[j + k] = v[k];
      s += v[k]; s2 += v[k] * v[k];
    }
  }
#pragma unroll
  for (int o = 32; o; o >>= 1) { s += __shfl_xor(s, o); s2 += __shfl_xor(s2, o); }
  if (lane == 0) { rbuf[wv] = s; rbuf[4 + wv] = s2; }
  __syncthreads();
  const float S  = rbuf[0] + rbuf[1] + rbuf[2] + rbuf[3];
  const float S2 = rbuf[4] + rbuf[5] + rbuf[6] + rbuf[7];
  const float mean = S * (1.f / (float)DMODEL);
  const float var  = S2 * (1.f / (float)DMODEL) - mean * mean;
  const float rstd = rsqrtf(var + 1e-5f);
  if (j < DMODEL) {
    float o[4];
#pragma unroll
    for (int k = 0; k < 4; ++k)
      o[k] = (buf[j + k] - mean) * rstd * w[j + k] + bvec[j + k];
    if (obf) {
      ushort4 ov;
      ov.x = f2bfu(o[0]); ov.y = f2bfu(o[1]); ov.z = f2bfu(o[2]); ov.w = f2bfu(o[3]);
      *(ushort4*)((unsigned short*)out + base + j) = ov;
    } else {
      float4 ov;
      ov.x = o[0]; ov.y = o[1]; ov.z = o[2]; ov.w = o[3];
      *(float4*)((float*)out + base + j) = ov;
    }
  }
}

// ---------------------------------------------------------------------------
extern "C" void kernel_launch(void* const* d_in, const int* in_sizes, int n_in,
                              void* d_out, int out_size, void* d_ws, size_t ws_size,
                              hipStream_t stream) {
  const float* src  = (const float*)d_in[0];
  const float* Wq   = (const float*)d_in[1];
  const float* bq   = (const float*)d_in[2];
  const float* Wk   = (const float*)d_in[3];
  const float* bk   = (const float*)d_in[4];
  const float* Wv   = (const float*)d_in[5];
  const float* bv   = (const float*)d_in[6];
  const float* Wo   = (const float*)d_in[7];
  const float* bo   = (const float*)d_in[8];
  const float* ln1w = (const float*)d_in[9];
  const float* ln1b = (const float*)d_in[10];
  const float* W1   = (const float*)d_in[11];
  const float* b1   = (const float*)d_in[12];
  const float* W2   = (const float*)d_in[13];
  const float* b2   = (const float*)d_in[14];
  const float* ln2w = (const float*)d_in[15];
  const float* ln2b = (const float*)d_in[16];
  (void)ws_size; (void)in_sizes; (void)n_in; (void)out_size;

  unsigned short* p = (unsigned short*)d_ws;
  const size_t SEG = (size_t)MROWS * DMODEL;
  unsigned short* srcb = p; p += SEG;
  unsigned short* qb   = p; p += SEG;   // Q; later split-K partial z0
  unsigned short* kb_  = p; p += SEG;   // K; later x1
  unsigned short* vbT  = p; p += SEG;   // V^T; later split-K partial z1
  unsigned short* ctx  = p; p += SEG;
  unsigned short* ff   = p; p += (size_t)MROWS * DFF_K;
  unsigned short* wqt  = p; p += (size_t)DMODEL * DMODEL;
  unsigned short* wkt  = p; p += (size_t)DMODEL * DMODEL;
  unsigned short* wvt  = p; p += (size_t)DMODEL * DMODEL;
  unsigned short* wot  = p; p += (size_t)DMODEL * DMODEL;
  unsigned short* w1t  = p; p += (size_t)DMODEL * DFF_K;
  unsigned short* w2t  = p; p += (size_t)DMODEL * DFF_K;
  unsigned short* x1 = kb_;
  // attention split-K scratch (regions dead during attention):
  //   ff  (25.17 MB) exactly fits [KSPLIT][B][H][S][DKH] f32 O-partials
  //   wqt (1.18 MB)  holds [KSPLIT][B][H][S] f32 l-partials (393 KB)
  float* opart = (float*)ff;
  float* lpart = (float*)wqt;

  dim3 blk(256);

  // 0: fused prep (convert + all weight transposes) -- one launch, was four
  prep_kernel<<<dim3(4800), blk, 0, stream>>>(
      src, srcb, Wq, Wk, Wv, Wo, wqt, wkt, wvt, wot, W1, w1t, W2, w2t);

  // 1: fused QKV projections (BN=128, 576 blocks; V written transposed)
  dim3 gqkv(MROWS / 128, DMODEL / 128, 3);     // 32 x 6 x 3
  qkv_gemm_kernel<<<gqkv, blk, 0, stream>>>(srcb, wqt, wkt, wvt, bq, bk, bv,
                                            qb, kb_, vbT);

  // 2: MFMA flash attention v4 (dbuf K/V, 1 barrier/tile) -> f32 partials
  dim3 ga(NHEAD, 2, (S_LEN / 128) * KSPLIT);   // 12 x 2 x 32 = 768 blocks
  flash_attn_mfma<<<ga, blk, 0, stream>>>(qb, kb_, vbT, opart, lpart);
  attn_combine_kernel<<<dim3(MROWS), blk, 0, stream>>>(opart, lpart, ctx);

  // 3: attn_out partials = ctx @ Wo + bo, BN=64 split-K=2 -> qb (z0), vbT (z1)
  dim3 gWo(MROWS / 128, DMODEL / 64, 2);       // 32 x 12 x 2 = 768
  mfma_gemm_kernel<64><<<gWo, blk, 0, stream>>>(ctx, wot, bo, qb,
                                                DMODEL, DMODEL, 0, DMODEL / 2, 2 * SEG);

  // 4: x1 = LN(srcb + p0 + p1)
  add_ln_kernel<<<dim3(MROWS), blk, 0, stream>>>(srcb, qb, vbT,
                                                 ln1w, ln1b, x1, 1, 1, 1);

  // 5: ff = relu(x1 @ W1 + b1)  (BN=128, 768 blocks)
  dim3 gF1(MROWS / 128, DFF_K / 128, 1);       // 32 x 24
  mfma_gemm_kernel<128><<<gF1, blk, 0, stream>>>(x1, w1t, b1, ff,
                                                 DMODEL, DFF_K, 1, DMODEL, 0);

  // 6: y2 partials = ff @ W2 + b2, BN=64 split-K=2 -> qb (z0), vbT (z1)
  dim3 gW2(MROWS / 128, DMODEL / 64, 2);       // 32 x 12 x 2 = 768
  mfma_gemm_kernel<64><<<gW2, blk, 0, stream>>>(ff, w2t, b2, qb,
                                                DFF_K, DMODEL, 0, DFF_K / 2, 2 * SEG);

  // 7: out = LN(x1 + p0 + p1)
  add_ln_kernel<<<dim3(MROWS), blk, 0, stream>>>(x1, qb, vbT,
                                                 ln2w, ln2b, (float*)d_out, 1, 1, 0);
}